// Round 11
// baseline (521.454 us; speedup 1.0000x reference)
//
#include <hip/hip_runtime.h>
#include <hip/hip_bf16.h>
#include <math.h>

// Problem constants
#define BB 2
#define SS 1024
#define DD 768
#define HH 12
#define DHH 64
#define MM 64
#define DFF 3072
#define BS (BB*SS)          // 2048 rows
#define EPS_LN 1e-5f
#define EPS_PHI 1e-6f
#define CC 64               // scan chunk length
#define NC (SS/CC)          // 16 chunks
#define NQ 3840             // q,k,v (2304) + proj_q (768) + proj_k (768)
#define PQOFF 2304
#define PKOFF 3072
#define VOFF  1536

typedef __hip_bfloat16 bf16;
using v8s = __attribute__((ext_vector_type(8))) short;   // 8 bf16 (MFMA A/B frag)
using v4f = __attribute__((ext_vector_type(4))) float;   // MFMA C/D frag

// ---------------------------------------------------------------------------
// All four weight transposes in ONE dispatch.
// ---------------------------------------------------------------------------
__global__ __launch_bounds__(256) void transpose_all_kernel(const float* __restrict__ w_attn,
                                                            const float* __restrict__ w_proj,
                                                            const float* __restrict__ w_fc,
                                                            const float* __restrict__ w_out,
                                                            bf16* __restrict__ wext_t,
                                                            bf16* __restrict__ wproj_t,
                                                            bf16* __restrict__ wfc_t,
                                                            bf16* __restrict__ wout_t) {
    int bid = blockIdx.x;
    const float* in; bf16* outp; int K, N, xt, yt;
    if (bid < 1728)      { in = w_attn; outp = wext_t;  K = 768;  N = 2304; xt = bid % 72;          yt = bid / 72; }
    else if (bid < 2304) { int b = bid - 1728; in = w_proj; outp = wproj_t; K = 768;  N = 768;  xt = b % 24; yt = b / 24; }
    else if (bid < 4608) { int b = bid - 2304; in = w_fc;   outp = wfc_t;   K = 768;  N = 3072; xt = b % 96; yt = b / 96; }
    else                 { int b = bid - 4608; in = w_out;  outp = wout_t;  K = 3072; N = 768;  xt = b % 24; yt = b / 24; }
    __shared__ float t[32][33];
    int tx = threadIdx.x & 31, ty = threadIdx.x >> 5;    // 32 x 8
    int n0 = xt * 32, k0 = yt * 32;
    #pragma unroll
    for (int i = ty; i < 32; i += 8)
        t[i][tx] = in[(size_t)(k0 + i) * N + n0 + tx];
    __syncthreads();
    #pragma unroll
    for (int i = ty; i < 32; i += 8)
        outp[(size_t)(n0 + i) * K + k0 + tx] = __float2bfloat16(t[tx][i]);
}

// ---------------------------------------------------------------------------
// Fused FAVOR+ projection weights (cols 2304..3839 of W_ext) + bias_ext.
// ---------------------------------------------------------------------------
__global__ __launch_bounds__(256) void fuse_feat_kernel(const float* __restrict__ w_attn,
                                                        const float* __restrict__ b_attn,
                                                        const float* __restrict__ wfeat,
                                                        bf16* __restrict__ bt_ext,
                                                        float* __restrict__ bias_ext) {
    __shared__ float wfT[64][65];   // wfT[d][m] = scale*wf[m][d]
    __shared__ float Wt[64][65];    // Wt[j][d]
    int t = threadIdx.x;
    int j0 = blockIdx.x * 64, h = blockIdx.y, isK = blockIdx.z;
    int base = isK * DD + h * DHH;
    const float scale = 0.35355339059327373f;  // 64^-0.25
    #pragma unroll
    for (int it = 0; it < 16; it++) {
        int idx = it * 256 + t;
        int m = idx >> 6, d = idx & 63;
        wfT[d][m] = scale * wfeat[m * DHH + d];
        Wt[idx >> 6][idx & 63] = w_attn[(size_t)(j0 + (idx >> 6)) * (3 * DD) + base + (idx & 63)];
    }
    __syncthreads();
    int jl = t & 63, mg = (t >> 6) * 16;
    for (int m = mg; m < mg + 16; m++) {
        float acc = 0.f;
        #pragma unroll 8
        for (int d = 0; d < 64; d++) acc += wfT[d][m] * Wt[jl][d];
        bt_ext[(size_t)(PQOFF + isK * DD + h * DHH + m) * DD + j0 + jl] = __float2bfloat16(acc);
    }
    if (blockIdx.x == 0 && t < 64) {
        float accb = 0.f;
        #pragma unroll 8
        for (int d = 0; d < 64; d++) accb += wfT[d][t] * b_attn[base + d];
        bias_ext[PQOFF + isK * DD + h * DHH + t] = accb;
    }
}

// ---------------------------------------------------------------------------
// LayerNorm: one block per row, 256 threads; f32 in -> bf16 out.
// ---------------------------------------------------------------------------
__global__ __launch_bounds__(256) void ln_kernel(const float* __restrict__ x,
                                                 const float* __restrict__ g,
                                                 const float* __restrict__ bta,
                                                 bf16* __restrict__ out) {
    int row = blockIdx.x;
    int t = threadIdx.x;
    const float* xr = x + (size_t)row * DD;
    float v0 = xr[t], v1 = xr[t + 256], v2 = xr[t + 512];
    float s = v0 + v1 + v2;
    float s2 = v0 * v0 + v1 * v1 + v2 * v2;
    #pragma unroll
    for (int off = 32; off > 0; off >>= 1) {
        s  += __shfl_xor(s,  off, 64);
        s2 += __shfl_xor(s2, off, 64);
    }
    __shared__ float ls[4], ls2[4];
    if ((t & 63) == 0) { ls[t >> 6] = s; ls2[t >> 6] = s2; }
    __syncthreads();
    s  = ls[0] + ls[1] + ls[2] + ls[3];
    s2 = ls2[0] + ls2[1] + ls2[2] + ls2[3];
    float mu  = s * (1.0f / DD);
    float var = s2 * (1.0f / DD) - mu * mu;
    float r = rsqrtf(var + EPS_LN);
    bf16* orow = out + (size_t)row * DD;
    orow[t]       = __float2bfloat16((v0 - mu) * r * g[t]       + bta[t]);
    orow[t + 256] = __float2bfloat16((v1 - mu) * r * g[t + 256] + bta[t + 256]);
    orow[t + 512] = __float2bfloat16((v2 - mu) * r * g[t + 512] + bta[t + 512]);
}

// ---------------------------------------------------------------------------
// Pipelined MFMA GEMM: C = A @ BT^T + bias (+gelu)(+res).
// TM=64, TN=64, BK=32, 4 waves (wave w owns rows 16w..16w+15).
// LDS double-buffer + distance-2 register prefetch, ONE barrier per iter:
//   iter kt: issue loads tile kt+2 -> r[cur]  (no wait)
//            store r[cur^1] (tile kt+1) -> lds[(kt+1)&1]  (vmcnt waits on a
//              load issued a full iteration ago -> latency hidden)
//            MFMA on lds[cur]; barrier.
// Race-safety: every store targets the buffer whose readers were fenced by
// the previous iteration's barrier.
// ---------------------------------------------------------------------------
__device__ inline float gelu_tanh(float x) {
    float x3 = x * x * x;
    float u = 0.7978845608028654f * (x + 0.044715f * x3);
    return 0.5f * x * (1.0f + tanhf(u));
}

template <int ACT, int HAS_RES, int OUT_BF16>
__global__ __launch_bounds__(256) void gemm_pipe_kernel(const bf16* __restrict__ A,
                                                        const bf16* __restrict__ BT,
                                                        const float* __restrict__ bias,
                                                        const float* __restrict__ res,
                                                        void* __restrict__ Cout,
                                                        int N, int K) {
    __shared__ bf16 Asl[2][64][40];
    __shared__ bf16 Bsl[2][64][40];
    int tid = threadIdx.x;
    int m0 = blockIdx.y * 64, n0 = blockIdx.x * 64;
    int wave = tid >> 6, lane = tid & 63;
    int qm = lane & 15, quad = lane >> 4;
    int sm = tid >> 2, sk = (tid & 3) * 8;
    const bf16* Ap = A  + (size_t)(m0 + sm) * K + sk;
    const bf16* Bp = BT + (size_t)(n0 + sm) * K + sk;
    int nk = K >> 5;   // BK=32; all K here are multiples of 64, nk >= 24

    uint4 ra[2], rb[2];
    ra[0] = *(const uint4*)(Ap);       rb[0] = *(const uint4*)(Bp);
    ra[1] = *(const uint4*)(Ap + 32);  rb[1] = *(const uint4*)(Bp + 32);
    *(uint4*)&Asl[0][sm][sk] = ra[0];
    *(uint4*)&Bsl[0][sm][sk] = rb[0];
    __syncthreads();

    v4f acc[4] = {{0.f,0.f,0.f,0.f},{0.f,0.f,0.f,0.f},{0.f,0.f,0.f,0.f},{0.f,0.f,0.f,0.f}};

    for (int kt = 0; kt < nk; kt++) {
        int cur = kt & 1;
        // 1) issue loads for tile kt+2 into r[cur] (its old contents were
        //    stored to LDS last iteration) — no wait here.
        if (kt + 2 < nk) {
            ra[cur] = *(const uint4*)(Ap + (size_t)(kt + 2) * 32);
            rb[cur] = *(const uint4*)(Bp + (size_t)(kt + 2) * 32);
        }
        // 2) store tile kt+1 (in r[cur^1], loaded one full iteration ago)
        if (kt + 1 < nk) {
            *(uint4*)&Asl[cur ^ 1][sm][sk] = ra[cur ^ 1];
            *(uint4*)&Bsl[cur ^ 1][sm][sk] = rb[cur ^ 1];
        }
        // 3) MFMA on current LDS buffer
        v8s a = *(const v8s*)&Asl[cur][wave * 16 + qm][quad * 8];
        #pragma unroll
        for (int t = 0; t < 4; t++) {
            v8s b = *(const v8s*)&Bsl[cur][t * 16 + qm][quad * 8];
            acc[t] = __builtin_amdgcn_mfma_f32_16x16x32_bf16(a, b, acc[t], 0, 0, 0);
        }
        // 4) fence buffer swap (skip after final tile)
        if (kt + 1 < nk) __syncthreads();
    }

    int col_l = lane & 15;
    #pragma unroll
    for (int t = 0; t < 4; t++) {
        int col = n0 + t * 16 + col_l;
        float bcol = bias[col];
        #pragma unroll
        for (int r = 0; r < 4; r++) {
            int row = m0 + wave * 16 + quad * 4 + r;
            float v = acc[t][r] + bcol;
            if (ACT == 1) v = gelu_tanh(v);
            if (HAS_RES) v += res[(size_t)row * N + col];
            if (OUT_BF16) ((bf16*)Cout)[(size_t)row * N + col] = __float2bfloat16(v);
            else          ((float*)Cout)[(size_t)row * N + col] = v;
        }
    }
}

// ---------------------------------------------------------------------------
// phi in place over proj columns of qkvp.
// ---------------------------------------------------------------------------
__global__ __launch_bounds__(256) void phi_exp_kernel(float* __restrict__ qkvp) {
    int s = blockIdx.x, z = blockIdx.z;
    int b = z >> 1, isK = z & 1;
    int t = threadIdx.x;
    int h = blockIdx.y * 4 + (t >> 6);
    int m = t & 63;
    size_t row = (size_t)b * SS + s;
    float qd = qkvp[row * NQ + isK * DD + h * DHH + m];
    float sq = qd * qd;
    #pragma unroll
    for (int off = 32; off > 0; off >>= 1) sq += __shfl_xor(sq, off, 64);
    sq *= (1.0f / 16.0f);
    size_t pidx = row * NQ + PQOFF + isK * DD + h * DHH + m;
    float proj = qkvp[pidx];
    qkvp[pidx] = __expf(proj - sq) * 0.125f + EPS_PHI;
}

// ---------------------------------------------------------------------------
// Scan phase 1 (MFMA): per (b,h,c): StateT[d][m] = V^T @ phik ; Sk[m] = col-sum.
// ---------------------------------------------------------------------------
__global__ __launch_bounds__(256) void scan_sums_mfma(const float* __restrict__ qkvp,
                                                      float* __restrict__ StateT,
                                                      float* __restrict__ Sk) {
    int c = blockIdx.x, h = blockIdx.y, b = blockIdx.z;
    int bh = b * HH + h;
    int t = threadIdx.x;
    __shared__ bf16 vt[64][72];   // V^T[d][s]
    __shared__ bf16 kt[64][72];   // phik^T[m][s]
    int sr = t >> 4, cq = (t & 15) * 4;
    #pragma unroll
    for (int i = 0; i < 4; i++) {
        int s = sr + 16 * i;
        size_t rowg = ((size_t)b * SS + c * CC + s) * NQ + h * DHH;
        float4 vv = *(const float4*)&qkvp[rowg + VOFF  + cq];
        float4 kv = *(const float4*)&qkvp[rowg + PKOFF + cq];
        vt[cq + 0][s] = __float2bfloat16(vv.x);
        vt[cq + 1][s] = __float2bfloat16(vv.y);
        vt[cq + 2][s] = __float2bfloat16(vv.z);
        vt[cq + 3][s] = __float2bfloat16(vv.w);
        kt[cq + 0][s] = __float2bfloat16(kv.x);
        kt[cq + 1][s] = __float2bfloat16(kv.y);
        kt[cq + 2][s] = __float2bfloat16(kv.z);
        kt[cq + 3][s] = __float2bfloat16(kv.w);
    }
    __syncthreads();
    int wave = t >> 6, lane = t & 63, qm = lane & 15, quad = lane >> 4;
    v4f acc[4] = {{0.f,0.f,0.f,0.f},{0.f,0.f,0.f,0.f},{0.f,0.f,0.f,0.f},{0.f,0.f,0.f,0.f}};
    #pragma unroll
    for (int k0 = 0; k0 < 64; k0 += 32) {
        v8s a = *(const v8s*)&vt[wave * 16 + qm][k0 + quad * 8];
        #pragma unroll
        for (int n = 0; n < 4; n++) {
            v8s bb = *(const v8s*)&kt[n * 16 + qm][k0 + quad * 8];
            acc[n] = __builtin_amdgcn_mfma_f32_16x16x32_bf16(a, bb, acc[n], 0, 0, 0);
        }
    }
    float* dst = StateT + ((size_t)bh * NC + c) * 4096;
    int col_l = lane & 15;
    #pragma unroll
    for (int n = 0; n < 4; n++)
        #pragma unroll
        for (int r = 0; r < 4; r++) {
            int d = wave * 16 + quad * 4 + r;
            dst[d * 64 + n * 16 + col_l] = acc[n][r];
        }
    if (t < 64) {
        float sum = 0.f;
        #pragma unroll 8
        for (int i = 0; i < 64; i++) sum += __bfloat162float(kt[t][i]);
        Sk[((size_t)bh * NC + c) * 64 + t] = sum;
    }
}

// ---------------------------------------------------------------------------
// Scan phase 2: in-place EXCLUSIVE prefix over chunks.
// ---------------------------------------------------------------------------
__global__ __launch_bounds__(256) void scan_prefix_kernel(float* __restrict__ Skv,
                                                          float* __restrict__ Sk) {
    int bh = blockIdx.y;
    int t = blockIdx.x * 256 + threadIdx.x;
    size_t base = (size_t)bh * NC * 4096 + t;
    float acc = 0.f;
    for (int c = 0; c < NC; c++) {
        float v = Skv[base + (size_t)c * 4096];
        Skv[base + (size_t)c * 4096] = acc;
        acc += v;
    }
    if (blockIdx.x == 0 && threadIdx.x < 64) {
        size_t b2 = (size_t)bh * NC * 64 + threadIdx.x;
        float a2 = 0.f;
        for (int c = 0; c < NC; c++) {
            float v = Sk[b2 + (size_t)c * 64];
            Sk[b2 + (size_t)c * 64] = a2;
            a2 += v;
        }
    }
}

// ---------------------------------------------------------------------------
// Scan phase 3 (MFMA): A1 = phiq@phik^T, mask tril -> P;
// acc = phiq@[StateT|SkPre]^T + P@[V|1]; tile4 col0 = den; attn = num/den.
// ---------------------------------------------------------------------------
__global__ __launch_bounds__(256) void scan_chunk_mfma(const float* __restrict__ qkvp,
                                                       const float* __restrict__ StateT,
                                                       const float* __restrict__ SkPre,
                                                       bf16* __restrict__ attn) {
    int c = blockIdx.x, h = blockIdx.y, b = blockIdx.z;
    int bh = b * HH + h;
    int t = threadIdx.x;
    __shared__ bf16 qs[64][72];
    __shared__ bf16 ks[64][72];
    __shared__ bf16 vt[80][72];
    __shared__ bf16 stl[80][72];
    __shared__ bf16 P[64][72];
    int sr = t >> 4, cq = (t & 15) * 4;
    const float* stg = StateT + ((size_t)bh * NC + c) * 4096;
    #pragma unroll
    for (int i = 0; i < 4; i++) {
        int s = sr + 16 * i;
        size_t rowg = ((size_t)b * SS + c * CC + s) * NQ + h * DHH;
        float4 qv = *(const float4*)&qkvp[rowg + PQOFF + cq];
        float4 kv = *(const float4*)&qkvp[rowg + PKOFF + cq];
        float4 vv = *(const float4*)&qkvp[rowg + VOFF  + cq];
        float4 sv = *(const float4*)&stg[s * 64 + cq];
        qs[s][cq + 0] = __float2bfloat16(qv.x);
        qs[s][cq + 1] = __float2bfloat16(qv.y);
        qs[s][cq + 2] = __float2bfloat16(qv.z);
        qs[s][cq + 3] = __float2bfloat16(qv.w);
        ks[s][cq + 0] = __float2bfloat16(kv.x);
        ks[s][cq + 1] = __float2bfloat16(kv.y);
        ks[s][cq + 2] = __float2bfloat16(kv.z);
        ks[s][cq + 3] = __float2bfloat16(kv.w);
        vt[cq + 0][s] = __float2bfloat16(vv.x);
        vt[cq + 1][s] = __float2bfloat16(vv.y);
        vt[cq + 2][s] = __float2bfloat16(vv.z);
        vt[cq + 3][s] = __float2bfloat16(vv.w);
        stl[s][cq + 0] = __float2bfloat16(sv.x);
        stl[s][cq + 1] = __float2bfloat16(sv.y);
        stl[s][cq + 2] = __float2bfloat16(sv.z);
        stl[s][cq + 3] = __float2bfloat16(sv.w);
    }
    {
        int rr = 64 + (t >> 4);
        bf16 one = __float2bfloat16(rr == 64 ? 1.f : 0.f);
        vt[rr][cq + 0] = one; vt[rr][cq + 1] = one;
        vt[rr][cq + 2] = one; vt[rr][cq + 3] = one;
        if (rr == 64) {
            const float* skp = SkPre + ((size_t)bh * NC + c) * 64;
            float4 s4 = *(const float4*)&skp[cq];
            stl[64][cq + 0] = __float2bfloat16(s4.x);
            stl[64][cq + 1] = __float2bfloat16(s4.y);
            stl[64][cq + 2] = __float2bfloat16(s4.z);
            stl[64][cq + 3] = __float2bfloat16(s4.w);
        } else {
            bf16 z = __float2bfloat16(0.f);
            stl[rr][cq + 0] = z; stl[rr][cq + 1] = z;
            stl[rr][cq + 2] = z; stl[rr][cq + 3] = z;
        }
    }
    __syncthreads();
    int wave = t >> 6, lane = t & 63, qm = lane & 15, quad = lane >> 4;
    int col_l = lane & 15;
    int row0 = wave * 16;

    v4f a1[4] = {{0.f,0.f,0.f,0.f},{0.f,0.f,0.f,0.f},{0.f,0.f,0.f,0.f},{0.f,0.f,0.f,0.f}};
    #pragma unroll
    for (int k0 = 0; k0 < 64; k0 += 32) {
        v8s a = *(const v8s*)&qs[row0 + qm][k0 + quad * 8];
        #pragma unroll
        for (int n = 0; n < 4; n++) {
            v8s bb = *(const v8s*)&ks[n * 16 + qm][k0 + quad * 8];
            a1[n] = __builtin_amdgcn_mfma_f32_16x16x32_bf16(a, bb, a1[n], 0, 0, 0);
        }
    }
    #pragma unroll
    for (int n = 0; n < 4; n++)
        #pragma unroll
        for (int r = 0; r < 4; r++) {
            int row = row0 + quad * 4 + r;
            int col = n * 16 + col_l;
            float v = (col <= row) ? a1[n][r] : 0.f;
            P[row][col] = __float2bfloat16(v);
        }
    v4f acc[5] = {{0.f,0.f,0.f,0.f},{0.f,0.f,0.f,0.f},{0.f,0.f,0.f,0.f},
                  {0.f,0.f,0.f,0.f},{0.f,0.f,0.f,0.f}};
    #pragma unroll
    for (int k0 = 0; k0 < 64; k0 += 32) {
        v8s aq = *(const v8s*)&qs[row0 + qm][k0 + quad * 8];
        v8s ap = *(const v8s*)&P [row0 + qm][k0 + quad * 8];
        #pragma unroll
        for (int n = 0; n < 5; n++) {
            v8s b1 = *(const v8s*)&stl[n * 16 + qm][k0 + quad * 8];
            v8s b2 = *(const v8s*)&vt [n * 16 + qm][k0 + quad * 8];
            acc[n] = __builtin_amdgcn_mfma_f32_16x16x32_bf16(aq, b1, acc[n], 0, 0, 0);
            acc[n] = __builtin_amdgcn_mfma_f32_16x16x32_bf16(ap, b2, acc[n], 0, 0, 0);
        }
    }
    float den[4];
    #pragma unroll
    for (int r = 0; r < 4; r++)
        den[r] = __shfl(acc[4][r], (lane >> 4) << 4, 64);
    #pragma unroll
    for (int n = 0; n < 4; n++)
        #pragma unroll
        for (int r = 0; r < 4; r++) {
            int srow = row0 + quad * 4 + r;
            int d = n * 16 + col_l;
            attn[((size_t)b * SS + c * CC + srow) * DD + h * DHH + d] =
                __float2bfloat16(acc[n][r] / den[r]);
        }
}

// ---------------------------------------------------------------------------
extern "C" void kernel_launch(void* const* d_in, const int* in_sizes, int n_in,
                              void* d_out, int out_size, void* d_ws, size_t ws_size,
                              hipStream_t stream) {
    const float* x      = (const float*)d_in[0];
    const float* ln1_g  = (const float*)d_in[1];
    const float* ln1_b  = (const float*)d_in[2];
    const float* w_attn = (const float*)d_in[3];
    const float* b_attn = (const float*)d_in[4];
    const float* w_feat = (const float*)d_in[5];
    const float* w_proj = (const float*)d_in[6];
    const float* b_proj = (const float*)d_in[7];
    const float* ln2_g  = (const float*)d_in[8];
    const float* ln2_b  = (const float*)d_in[9];
    const float* w_fc   = (const float*)d_in[10];
    const float* b_fc   = (const float*)d_in[11];
    const float* w_out  = (const float*)d_in[12];
    const float* b_out  = (const float*)d_in[13];
    float* out = (float*)d_out;

    // f32 region
    float* ws = (float*)d_ws;
    size_t off = 0;
    float* buf_qkvp = ws + off; off += (size_t)BS * NQ;            // 7.86M f32
    float* buf_x1   = ws + off; off += (size_t)BS * DD;            // 1.57M
    float* buf_sk   = ws + off; off += (size_t)BB * HH * NC * MM;  // 24.6K
    float* bias_ext = ws + off; off += NQ;
    // bf16 region
    bf16* wb = (bf16*)(ws + off);
    size_t boff = 0;
    bf16* buf_a_bf    = wb + boff; boff += (size_t)BS * DD;
    bf16* buf_attn_bf = wb + boff; boff += (size_t)BS * DD;
    bf16* wext_t      = wb + boff; boff += (size_t)NQ * DD;
    bf16* wproj_t     = wb + boff; boff += (size_t)DD * DD;
    bf16* wfc_t       = wb + boff; boff += (size_t)DFF * DD;
    bf16* wout_t      = wb + boff; boff += (size_t)DD * DFF;
    // Aliases: StateT (1.57M f32) over buf_x1; fc bf16 over dead qkvp head.
    float* buf_skv   = buf_x1;
    bf16*  buf_fc_bf = (bf16*)buf_qkvp;

    // 0) weight prep (one transpose dispatch + fused FAVOR+ cols + bias copy)
    transpose_all_kernel<<<6912, 256, 0, stream>>>(w_attn, w_proj, w_fc, w_out,
                                                   wext_t, wproj_t, wfc_t, wout_t);
    fuse_feat_kernel<<<dim3(DD / 64, HH, 2), 256, 0, stream>>>(w_attn, b_attn, w_feat, wext_t, bias_ext);
    hipMemcpyAsync(bias_ext, b_attn, 3 * DD * sizeof(float), hipMemcpyDeviceToDevice, stream);

    // 1) a = LN1(x) -> bf16
    ln_kernel<<<BS, 256, 0, stream>>>(x, ln1_g, ln1_b, buf_a_bf);
    // 2) [qkv | proj_q | proj_k] = a @ W_ext + bias_ext  (1920 blocks)
    gemm_pipe_kernel<0, 0, 0><<<dim3(NQ / 64, BS / 64), 256, 0, stream>>>(
        buf_a_bf, wext_t, bias_ext, nullptr, buf_qkvp, NQ, DD);
    // 3) phi in place
    phi_exp_kernel<<<dim3(SS, 3, 2 * BB), 256, 0, stream>>>(buf_qkvp);
    // 4a) per-chunk sums (MFMA)
    scan_sums_mfma<<<dim3(NC, HH, BB), 256, 0, stream>>>(buf_qkvp, buf_skv, buf_sk);
    // 4b) exclusive prefix over chunks
    scan_prefix_kernel<<<dim3(4096 / 256, BB * HH), 256, 0, stream>>>(buf_skv, buf_sk);
    // 4c) per-chunk masked-MFMA scan -> attn (bf16)
    scan_chunk_mfma<<<dim3(NC, HH, BB), 256, 0, stream>>>(
        buf_qkvp, buf_skv, buf_sk, buf_attn_bf);
    // 5) x1 = x + attn @ w_proj + b_proj  (384 blocks)
    gemm_pipe_kernel<0, 1, 0><<<dim3(DD / 64, BS / 64), 256, 0, stream>>>(
        buf_attn_bf, wproj_t, b_proj, x, buf_x1, DD, DD);
    // 6) m = LN2(x1) -> bf16
    ln_kernel<<<BS, 256, 0, stream>>>(buf_x1, ln2_g, ln2_b, buf_a_bf);
    // 7) fc = gelu(m @ w_fc + b_fc) -> bf16  (1536 blocks)
    gemm_pipe_kernel<1, 0, 1><<<dim3(DFF / 64, BS / 64), 256, 0, stream>>>(
        buf_a_bf, wfc_t, b_fc, nullptr, buf_fc_bf, DFF, DD);
    // 8) out = x1 + fc @ w_out + b_out  (384 blocks, K=3072)
    gemm_pipe_kernel<0, 1, 0><<<dim3(DD / 64, BS / 64), 256, 0, stream>>>(
        buf_fc_bf, wout_t, b_out, buf_x1, out, DD, DFF);
}

// Round 12
// 418.522 us; speedup vs baseline: 1.2459x; 1.2459x over previous
//
#include <hip/hip_runtime.h>
#include <hip/hip_bf16.h>
#include <math.h>

// Problem constants
#define BB 2
#define SS 1024
#define DD 768
#define HH 12
#define DHH 64
#define MM 64
#define DFF 3072
#define BS (BB*SS)          // 2048 rows
#define EPS_LN 1e-5f
#define EPS_PHI 1e-6f
#define CC 64               // scan chunk length
#define NC (SS/CC)          // 16 chunks
#define NQ 3840             // q,k,v (2304) + proj_q (768) + proj_k (768)
#define PQOFF 2304
#define PKOFF 3072
#define VOFF  1536

typedef __hip_bfloat16 bf16;
using v8s = __attribute__((ext_vector_type(8))) short;   // 8 bf16 (MFMA A/B frag)
using v4f = __attribute__((ext_vector_type(4))) float;   // MFMA C/D frag

// ---------------------------------------------------------------------------
// All four weight transposes in ONE dispatch.
// ---------------------------------------------------------------------------
__global__ __launch_bounds__(256) void transpose_all_kernel(const float* __restrict__ w_attn,
                                                            const float* __restrict__ w_proj,
                                                            const float* __restrict__ w_fc,
                                                            const float* __restrict__ w_out,
                                                            bf16* __restrict__ wext_t,
                                                            bf16* __restrict__ wproj_t,
                                                            bf16* __restrict__ wfc_t,
                                                            bf16* __restrict__ wout_t) {
    int bid = blockIdx.x;
    const float* in; bf16* outp; int K, N, xt, yt;
    if (bid < 1728)      { in = w_attn; outp = wext_t;  K = 768;  N = 2304; xt = bid % 72;          yt = bid / 72; }
    else if (bid < 2304) { int b = bid - 1728; in = w_proj; outp = wproj_t; K = 768;  N = 768;  xt = b % 24; yt = b / 24; }
    else if (bid < 4608) { int b = bid - 2304; in = w_fc;   outp = wfc_t;   K = 768;  N = 3072; xt = b % 96; yt = b / 96; }
    else                 { int b = bid - 4608; in = w_out;  outp = wout_t;  K = 3072; N = 768;  xt = b % 24; yt = b / 24; }
    __shared__ float t[32][33];
    int tx = threadIdx.x & 31, ty = threadIdx.x >> 5;    // 32 x 8
    int n0 = xt * 32, k0 = yt * 32;
    #pragma unroll
    for (int i = ty; i < 32; i += 8)
        t[i][tx] = in[(size_t)(k0 + i) * N + n0 + tx];
    __syncthreads();
    #pragma unroll
    for (int i = ty; i < 32; i += 8)
        outp[(size_t)(n0 + i) * K + k0 + tx] = __float2bfloat16(t[tx][i]);
}

// ---------------------------------------------------------------------------
// Fused FAVOR+ projection weights (cols 2304..3839 of W_ext) + bias_ext.
// ---------------------------------------------------------------------------
__global__ __launch_bounds__(256) void fuse_feat_kernel(const float* __restrict__ w_attn,
                                                        const float* __restrict__ b_attn,
                                                        const float* __restrict__ wfeat,
                                                        bf16* __restrict__ bt_ext,
                                                        float* __restrict__ bias_ext) {
    __shared__ float wfT[64][65];   // wfT[d][m] = scale*wf[m][d]
    __shared__ float Wt[64][65];    // Wt[j][d]
    int t = threadIdx.x;
    int j0 = blockIdx.x * 64, h = blockIdx.y, isK = blockIdx.z;
    int base = isK * DD + h * DHH;
    const float scale = 0.35355339059327373f;  // 64^-0.25
    #pragma unroll
    for (int it = 0; it < 16; it++) {
        int idx = it * 256 + t;
        int m = idx >> 6, d = idx & 63;
        wfT[d][m] = scale * wfeat[m * DHH + d];
        Wt[idx >> 6][idx & 63] = w_attn[(size_t)(j0 + (idx >> 6)) * (3 * DD) + base + (idx & 63)];
    }
    __syncthreads();
    int jl = t & 63, mg = (t >> 6) * 16;
    for (int m = mg; m < mg + 16; m++) {
        float acc = 0.f;
        #pragma unroll 8
        for (int d = 0; d < 64; d++) acc += wfT[d][m] * Wt[jl][d];
        bt_ext[(size_t)(PQOFF + isK * DD + h * DHH + m) * DD + j0 + jl] = __float2bfloat16(acc);
    }
    if (blockIdx.x == 0 && t < 64) {
        float accb = 0.f;
        #pragma unroll 8
        for (int d = 0; d < 64; d++) accb += wfT[d][t] * b_attn[base + d];
        bias_ext[PQOFF + isK * DD + h * DHH + t] = accb;
    }
}

// ---------------------------------------------------------------------------
// LayerNorm: one block per row, 256 threads; f32 in -> bf16 out.
// ---------------------------------------------------------------------------
__global__ __launch_bounds__(256) void ln_kernel(const float* __restrict__ x,
                                                 const float* __restrict__ g,
                                                 const float* __restrict__ bta,
                                                 bf16* __restrict__ out) {
    int row = blockIdx.x;
    int t = threadIdx.x;
    const float* xr = x + (size_t)row * DD;
    float v0 = xr[t], v1 = xr[t + 256], v2 = xr[t + 512];
    float s = v0 + v1 + v2;
    float s2 = v0 * v0 + v1 * v1 + v2 * v2;
    #pragma unroll
    for (int off = 32; off > 0; off >>= 1) {
        s  += __shfl_xor(s,  off, 64);
        s2 += __shfl_xor(s2, off, 64);
    }
    __shared__ float ls[4], ls2[4];
    if ((t & 63) == 0) { ls[t >> 6] = s; ls2[t >> 6] = s2; }
    __syncthreads();
    s  = ls[0] + ls[1] + ls[2] + ls[3];
    s2 = ls2[0] + ls2[1] + ls2[2] + ls2[3];
    float mu  = s * (1.0f / DD);
    float var = s2 * (1.0f / DD) - mu * mu;
    float r = rsqrtf(var + EPS_LN);
    bf16* orow = out + (size_t)row * DD;
    orow[t]       = __float2bfloat16((v0 - mu) * r * g[t]       + bta[t]);
    orow[t + 256] = __float2bfloat16((v1 - mu) * r * g[t + 256] + bta[t + 256]);
    orow[t + 512] = __float2bfloat16((v2 - mu) * r * g[t + 512] + bta[t + 512]);
}

// ---------------------------------------------------------------------------
// DIRECT MFMA GEMM — no LDS, no barriers. C = A @ BT^T + bias (+gelu)(+res).
// Rationale (r11 post-mortem): the LDS-staged K-loop serializes on a
// compiler-emitted s_waitcnt vmcnt(0) before each LDS store/barrier,
// costing one full miss latency per K-iter (~531 ns measured). The MFMA
// A/B fragment is 8 CONTIGUOUS bf16 per lane, so each wave loads its
// fragments straight from global (1 dwordx4/lane), the compiler pipelines
// across unrolled iterations with fine vmcnt(N), and waves slip freely.
// TM=64, TN=64, 4 waves in 2x2: wave w -> rows (w&1)*32..+31, cols
// (w>>1)*32..+31 (2 row-tiles x 2 col-tiles, 4 MFMAs/iter). A/B each read
// by 2 waves -> 2x duplication, absorbed by L1/L2.
// K is a template constant so the loop unrolls.
// ---------------------------------------------------------------------------
__device__ inline float gelu_tanh(float x) {
    float x3 = x * x * x;
    float u = 0.7978845608028654f * (x + 0.044715f * x3);
    return 0.5f * x * (1.0f + tanhf(u));
}

template <int K, int ACT, int HAS_RES, int OUT_BF16>
__global__ __launch_bounds__(256) void gemm_direct_kernel(const bf16* __restrict__ A,
                                                          const bf16* __restrict__ BT,
                                                          const float* __restrict__ bias,
                                                          const float* __restrict__ res,
                                                          void* __restrict__ Cout,
                                                          int N) {
    int tid = threadIdx.x;
    int m0 = blockIdx.y * 64, n0 = blockIdx.x * 64;
    int wave = tid >> 6, lane = tid & 63;
    int qm = lane & 15, quad = lane >> 4;
    int rowb = (wave & 1) * 32;    // wave's row half
    int colb = (wave >> 1) * 32;   // wave's col half

    // per-lane fragment base pointers (8 contiguous bf16 each)
    const bf16* ap0 = A  + (size_t)(m0 + rowb + qm)      * K + quad * 8;
    const bf16* ap1 = A  + (size_t)(m0 + rowb + 16 + qm) * K + quad * 8;
    const bf16* bp0 = BT + (size_t)(n0 + colb + qm)      * K + quad * 8;
    const bf16* bp1 = BT + (size_t)(n0 + colb + 16 + qm) * K + quad * 8;

    v4f acc[2][2] = {};

    #pragma unroll 4
    for (int k0 = 0; k0 < K; k0 += 32) {
        v8s a0 = *(const v8s*)(ap0 + k0);
        v8s a1 = *(const v8s*)(ap1 + k0);
        v8s b0 = *(const v8s*)(bp0 + k0);
        v8s b1 = *(const v8s*)(bp1 + k0);
        acc[0][0] = __builtin_amdgcn_mfma_f32_16x16x32_bf16(a0, b0, acc[0][0], 0, 0, 0);
        acc[0][1] = __builtin_amdgcn_mfma_f32_16x16x32_bf16(a0, b1, acc[0][1], 0, 0, 0);
        acc[1][0] = __builtin_amdgcn_mfma_f32_16x16x32_bf16(a1, b0, acc[1][0], 0, 0, 0);
        acc[1][1] = __builtin_amdgcn_mfma_f32_16x16x32_bf16(a1, b1, acc[1][1], 0, 0, 0);
    }

    #pragma unroll
    for (int rt = 0; rt < 2; rt++)
        #pragma unroll
        for (int ct = 0; ct < 2; ct++) {
            int col = n0 + colb + ct * 16 + qm;
            float bcol = bias[col];
            #pragma unroll
            for (int r = 0; r < 4; r++) {
                int row = m0 + rowb + rt * 16 + quad * 4 + r;
                float v = acc[rt][ct][r] + bcol;
                if (ACT == 1) v = gelu_tanh(v);
                if (HAS_RES) v += res[(size_t)row * N + col];
                if (OUT_BF16) ((bf16*)Cout)[(size_t)row * N + col] = __float2bfloat16(v);
                else          ((float*)Cout)[(size_t)row * N + col] = v;
            }
        }
}

// ---------------------------------------------------------------------------
// phi in place over proj columns of qkvp.
// ---------------------------------------------------------------------------
__global__ __launch_bounds__(256) void phi_exp_kernel(float* __restrict__ qkvp) {
    int s = blockIdx.x, z = blockIdx.z;
    int b = z >> 1, isK = z & 1;
    int t = threadIdx.x;
    int h = blockIdx.y * 4 + (t >> 6);
    int m = t & 63;
    size_t row = (size_t)b * SS + s;
    float qd = qkvp[row * NQ + isK * DD + h * DHH + m];
    float sq = qd * qd;
    #pragma unroll
    for (int off = 32; off > 0; off >>= 1) sq += __shfl_xor(sq, off, 64);
    sq *= (1.0f / 16.0f);
    size_t pidx = row * NQ + PQOFF + isK * DD + h * DHH + m;
    float proj = qkvp[pidx];
    qkvp[pidx] = __expf(proj - sq) * 0.125f + EPS_PHI;
}

// ---------------------------------------------------------------------------
// Scan phase 1 (MFMA): per (b,h,c): StateT[d][m] = V^T @ phik ; Sk[m] = col-sum.
// ---------------------------------------------------------------------------
__global__ __launch_bounds__(256) void scan_sums_mfma(const float* __restrict__ qkvp,
                                                      float* __restrict__ StateT,
                                                      float* __restrict__ Sk) {
    int c = blockIdx.x, h = blockIdx.y, b = blockIdx.z;
    int bh = b * HH + h;
    int t = threadIdx.x;
    __shared__ bf16 vt[64][72];   // V^T[d][s]
    __shared__ bf16 kt[64][72];   // phik^T[m][s]
    int sr = t >> 4, cq = (t & 15) * 4;
    #pragma unroll
    for (int i = 0; i < 4; i++) {
        int s = sr + 16 * i;
        size_t rowg = ((size_t)b * SS + c * CC + s) * NQ + h * DHH;
        float4 vv = *(const float4*)&qkvp[rowg + VOFF  + cq];
        float4 kv = *(const float4*)&qkvp[rowg + PKOFF + cq];
        vt[cq + 0][s] = __float2bfloat16(vv.x);
        vt[cq + 1][s] = __float2bfloat16(vv.y);
        vt[cq + 2][s] = __float2bfloat16(vv.z);
        vt[cq + 3][s] = __float2bfloat16(vv.w);
        kt[cq + 0][s] = __float2bfloat16(kv.x);
        kt[cq + 1][s] = __float2bfloat16(kv.y);
        kt[cq + 2][s] = __float2bfloat16(kv.z);
        kt[cq + 3][s] = __float2bfloat16(kv.w);
    }
    __syncthreads();
    int wave = t >> 6, lane = t & 63, qm = lane & 15, quad = lane >> 4;
    v4f acc[4] = {{0.f,0.f,0.f,0.f},{0.f,0.f,0.f,0.f},{0.f,0.f,0.f,0.f},{0.f,0.f,0.f,0.f}};
    #pragma unroll
    for (int k0 = 0; k0 < 64; k0 += 32) {
        v8s a = *(const v8s*)&vt[wave * 16 + qm][k0 + quad * 8];
        #pragma unroll
        for (int n = 0; n < 4; n++) {
            v8s bb = *(const v8s*)&kt[n * 16 + qm][k0 + quad * 8];
            acc[n] = __builtin_amdgcn_mfma_f32_16x16x32_bf16(a, bb, acc[n], 0, 0, 0);
        }
    }
    float* dst = StateT + ((size_t)bh * NC + c) * 4096;
    int col_l = lane & 15;
    #pragma unroll
    for (int n = 0; n < 4; n++)
        #pragma unroll
        for (int r = 0; r < 4; r++) {
            int d = wave * 16 + quad * 4 + r;
            dst[d * 64 + n * 16 + col_l] = acc[n][r];
        }
    if (t < 64) {
        float sum = 0.f;
        #pragma unroll 8
        for (int i = 0; i < 64; i++) sum += __bfloat162float(kt[t][i]);
        Sk[((size_t)bh * NC + c) * 64 + t] = sum;
    }
}

// ---------------------------------------------------------------------------
// Scan phase 2: in-place EXCLUSIVE prefix over chunks.
// ---------------------------------------------------------------------------
__global__ __launch_bounds__(256) void scan_prefix_kernel(float* __restrict__ Skv,
                                                          float* __restrict__ Sk) {
    int bh = blockIdx.y;
    int t = blockIdx.x * 256 + threadIdx.x;
    size_t base = (size_t)bh * NC * 4096 + t;
    float acc = 0.f;
    for (int c = 0; c < NC; c++) {
        float v = Skv[base + (size_t)c * 4096];
        Skv[base + (size_t)c * 4096] = acc;
        acc += v;
    }
    if (blockIdx.x == 0 && threadIdx.x < 64) {
        size_t b2 = (size_t)bh * NC * 64 + threadIdx.x;
        float a2 = 0.f;
        for (int c = 0; c < NC; c++) {
            float v = Sk[b2 + (size_t)c * 64];
            Sk[b2 + (size_t)c * 64] = a2;
            a2 += v;
        }
    }
}

// ---------------------------------------------------------------------------
// Scan phase 3 (MFMA): A1 = phiq@phik^T, mask tril -> P;
// acc = phiq@[StateT|SkPre]^T + P@[V|1]; tile4 col0 = den; attn = num/den.
// ---------------------------------------------------------------------------
__global__ __launch_bounds__(256) void scan_chunk_mfma(const float* __restrict__ qkvp,
                                                       const float* __restrict__ StateT,
                                                       const float* __restrict__ SkPre,
                                                       bf16* __restrict__ attn) {
    int c = blockIdx.x, h = blockIdx.y, b = blockIdx.z;
    int bh = b * HH + h;
    int t = threadIdx.x;
    __shared__ bf16 qs[64][72];
    __shared__ bf16 ks[64][72];
    __shared__ bf16 vt[80][72];
    __shared__ bf16 stl[80][72];
    __shared__ bf16 P[64][72];
    int sr = t >> 4, cq = (t & 15) * 4;
    const float* stg = StateT + ((size_t)bh * NC + c) * 4096;
    #pragma unroll
    for (int i = 0; i < 4; i++) {
        int s = sr + 16 * i;
        size_t rowg = ((size_t)b * SS + c * CC + s) * NQ + h * DHH;
        float4 qv = *(const float4*)&qkvp[rowg + PQOFF + cq];
        float4 kv = *(const float4*)&qkvp[rowg + PKOFF + cq];
        float4 vv = *(const float4*)&qkvp[rowg + VOFF  + cq];
        float4 sv = *(const float4*)&stg[s * 64 + cq];
        qs[s][cq + 0] = __float2bfloat16(qv.x);
        qs[s][cq + 1] = __float2bfloat16(qv.y);
        qs[s][cq + 2] = __float2bfloat16(qv.z);
        qs[s][cq + 3] = __float2bfloat16(qv.w);
        ks[s][cq + 0] = __float2bfloat16(kv.x);
        ks[s][cq + 1] = __float2bfloat16(kv.y);
        ks[s][cq + 2] = __float2bfloat16(kv.z);
        ks[s][cq + 3] = __float2bfloat16(kv.w);
        vt[cq + 0][s] = __float2bfloat16(vv.x);
        vt[cq + 1][s] = __float2bfloat16(vv.y);
        vt[cq + 2][s] = __float2bfloat16(vv.z);
        vt[cq + 3][s] = __float2bfloat16(vv.w);
        stl[s][cq + 0] = __float2bfloat16(sv.x);
        stl[s][cq + 1] = __float2bfloat16(sv.y);
        stl[s][cq + 2] = __float2bfloat16(sv.z);
        stl[s][cq + 3] = __float2bfloat16(sv.w);
    }
    {
        int rr = 64 + (t >> 4);
        bf16 one = __float2bfloat16(rr == 64 ? 1.f : 0.f);
        vt[rr][cq + 0] = one; vt[rr][cq + 1] = one;
        vt[rr][cq + 2] = one; vt[rr][cq + 3] = one;
        if (rr == 64) {
            const float* skp = SkPre + ((size_t)bh * NC + c) * 64;
            float4 s4 = *(const float4*)&skp[cq];
            stl[64][cq + 0] = __float2bfloat16(s4.x);
            stl[64][cq + 1] = __float2bfloat16(s4.y);
            stl[64][cq + 2] = __float2bfloat16(s4.z);
            stl[64][cq + 3] = __float2bfloat16(s4.w);
        } else {
            bf16 z = __float2bfloat16(0.f);
            stl[rr][cq + 0] = z; stl[rr][cq + 1] = z;
            stl[rr][cq + 2] = z; stl[rr][cq + 3] = z;
        }
    }
    __syncthreads();
    int wave = t >> 6, lane = t & 63, qm = lane & 15, quad = lane >> 4;
    int col_l = lane & 15;
    int row0 = wave * 16;

    v4f a1[4] = {{0.f,0.f,0.f,0.f},{0.f,0.f,0.f,0.f},{0.f,0.f,0.f,0.f},{0.f,0.f,0.f,0.f}};
    #pragma unroll
    for (int k0 = 0; k0 < 64; k0 += 32) {
        v8s a = *(const v8s*)&qs[row0 + qm][k0 + quad * 8];
        #pragma unroll
        for (int n = 0; n < 4; n++) {
            v8s bb = *(const v8s*)&ks[n * 16 + qm][k0 + quad * 8];
            a1[n] = __builtin_amdgcn_mfma_f32_16x16x32_bf16(a, bb, a1[n], 0, 0, 0);
        }
    }
    #pragma unroll
    for (int n = 0; n < 4; n++)
        #pragma unroll
        for (int r = 0; r < 4; r++) {
            int row = row0 + quad * 4 + r;
            int col = n * 16 + col_l;
            float v = (col <= row) ? a1[n][r] : 0.f;
            P[row][col] = __float2bfloat16(v);
        }
    v4f acc[5] = {{0.f,0.f,0.f,0.f},{0.f,0.f,0.f,0.f},{0.f,0.f,0.f,0.f},
                  {0.f,0.f,0.f,0.f},{0.f,0.f,0.f,0.f}};
    #pragma unroll
    for (int k0 = 0; k0 < 64; k0 += 32) {
        v8s aq = *(const v8s*)&qs[row0 + qm][k0 + quad * 8];
        v8s ap = *(const v8s*)&P [row0 + qm][k0 + quad * 8];
        #pragma unroll
        for (int n = 0; n < 5; n++) {
            v8s b1 = *(const v8s*)&stl[n * 16 + qm][k0 + quad * 8];
            v8s b2 = *(const v8s*)&vt [n * 16 + qm][k0 + quad * 8];
            acc[n] = __builtin_amdgcn_mfma_f32_16x16x32_bf16(aq, b1, acc[n], 0, 0, 0);
            acc[n] = __builtin_amdgcn_mfma_f32_16x16x32_bf16(ap, b2, acc[n], 0, 0, 0);
        }
    }
    float den[4];
    #pragma unroll
    for (int r = 0; r < 4; r++)
        den[r] = __shfl(acc[4][r], (lane >> 4) << 4, 64);
    #pragma unroll
    for (int n = 0; n < 4; n++)
        #pragma unroll
        for (int r = 0; r < 4; r++) {
            int srow = row0 + quad * 4 + r;
            int d = n * 16 + col_l;
            attn[((size_t)b * SS + c * CC + srow) * DD + h * DHH + d] =
                __float2bfloat16(acc[n][r] / den[r]);
        }
}

// ---------------------------------------------------------------------------
extern "C" void kernel_launch(void* const* d_in, const int* in_sizes, int n_in,
                              void* d_out, int out_size, void* d_ws, size_t ws_size,
                              hipStream_t stream) {
    const float* x      = (const float*)d_in[0];
    const float* ln1_g  = (const float*)d_in[1];
    const float* ln1_b  = (const float*)d_in[2];
    const float* w_attn = (const float*)d_in[3];
    const float* b_attn = (const float*)d_in[4];
    const float* w_feat = (const float*)d_in[5];
    const float* w_proj = (const float*)d_in[6];
    const float* b_proj = (const float*)d_in[7];
    const float* ln2_g  = (const float*)d_in[8];
    const float* ln2_b  = (const float*)d_in[9];
    const float* w_fc   = (const float*)d_in[10];
    const float* b_fc   = (const float*)d_in[11];
    const float* w_out  = (const float*)d_in[12];
    const float* b_out  = (const float*)d_in[13];
    float* out = (float*)d_out;

    // f32 region
    float* ws = (float*)d_ws;
    size_t off = 0;
    float* buf_qkvp = ws + off; off += (size_t)BS * NQ;            // 7.86M f32
    float* buf_x1   = ws + off; off += (size_t)BS * DD;            // 1.57M
    float* buf_sk   = ws + off; off += (size_t)BB * HH * NC * MM;  // 24.6K
    float* bias_ext = ws + off; off += NQ;
    // bf16 region
    bf16* wb = (bf16*)(ws + off);
    size_t boff = 0;
    bf16* buf_a_bf    = wb + boff; boff += (size_t)BS * DD;
    bf16* buf_attn_bf = wb + boff; boff += (size_t)BS * DD;
    bf16* wext_t      = wb + boff; boff += (size_t)NQ * DD;
    bf16* wproj_t     = wb + boff; boff += (size_t)DD * DD;
    bf16* wfc_t       = wb + boff; boff += (size_t)DFF * DD;
    bf16* wout_t      = wb + boff; boff += (size_t)DD * DFF;
    // Aliases: StateT (1.57M f32) over buf_x1; fc bf16 over dead qkvp head.
    float* buf_skv   = buf_x1;
    bf16*  buf_fc_bf = (bf16*)buf_qkvp;

    // 0) weight prep (one transpose dispatch + fused FAVOR+ cols + bias copy)
    transpose_all_kernel<<<6912, 256, 0, stream>>>(w_attn, w_proj, w_fc, w_out,
                                                   wext_t, wproj_t, wfc_t, wout_t);
    fuse_feat_kernel<<<dim3(DD / 64, HH, 2), 256, 0, stream>>>(w_attn, b_attn, w_feat, wext_t, bias_ext);
    hipMemcpyAsync(bias_ext, b_attn, 3 * DD * sizeof(float), hipMemcpyDeviceToDevice, stream);

    // 1) a = LN1(x) -> bf16
    ln_kernel<<<BS, 256, 0, stream>>>(x, ln1_g, ln1_b, buf_a_bf);
    // 2) [qkv | proj_q | proj_k] = a @ W_ext + bias_ext  (1920 blocks, K=768)
    gemm_direct_kernel<768, 0, 0, 0><<<dim3(NQ / 64, BS / 64), 256, 0, stream>>>(
        buf_a_bf, wext_t, bias_ext, nullptr, buf_qkvp, NQ);
    // 3) phi in place
    phi_exp_kernel<<<dim3(SS, 3, 2 * BB), 256, 0, stream>>>(buf_qkvp);
    // 4a) per-chunk sums (MFMA)
    scan_sums_mfma<<<dim3(NC, HH, BB), 256, 0, stream>>>(buf_qkvp, buf_skv, buf_sk);
    // 4b) exclusive prefix over chunks
    scan_prefix_kernel<<<dim3(4096 / 256, BB * HH), 256, 0, stream>>>(buf_skv, buf_sk);
    // 4c) per-chunk masked-MFMA scan -> attn (bf16)
    scan_chunk_mfma<<<dim3(NC, HH, BB), 256, 0, stream>>>(
        buf_qkvp, buf_skv, buf_sk, buf_attn_bf);
    // 5) x1 = x + attn @ w_proj + b_proj  (384 blocks, K=768)
    gemm_direct_kernel<768, 0, 1, 0><<<dim3(DD / 64, BS / 64), 256, 0, stream>>>(
        buf_attn_bf, wproj_t, b_proj, x, buf_x1, DD);
    // 6) m = LN2(x1) -> bf16
    ln_kernel<<<BS, 256, 0, stream>>>(buf_x1, ln2_g, ln2_b, buf_a_bf);
    // 7) fc = gelu(m @ w_fc + b_fc) -> bf16  (1536 blocks, K=768)
    gemm_direct_kernel<768, 1, 0, 1><<<dim3(DFF / 64, BS / 64), 256, 0, stream>>>(
        buf_a_bf, wfc_t, b_fc, nullptr, buf_fc_bf, DFF);
    // 8) out = x1 + fc @ w_out + b_out  (384 blocks, K=3072)
    gemm_direct_kernel<3072, 0, 1, 0><<<dim3(DD / 64, BS / 64), 256, 0, stream>>>(
        buf_fc_bf, wout_t, b_out, buf_x1, out, DD);
}

// Round 13
// 280.163 us; speedup vs baseline: 1.8613x; 1.4939x over previous
//
#include <hip/hip_runtime.h>
#include <hip/hip_bf16.h>
#include <math.h>

// Problem constants
#define BB 2
#define SS 1024
#define DD 768
#define HH 12
#define DHH 64
#define MM 64
#define DFF 3072
#define BS (BB*SS)          // 2048 rows
#define EPS_LN 1e-5f
#define EPS_PHI 1e-6f
#define CC 64               // scan chunk length
#define NC (SS/CC)          // 16 chunks
#define NQ 3840             // q,k,v (2304) + proj_q (768) + proj_k (768)
#define PQOFF 2304
#define PKOFF 3072
#define VOFF  1536

typedef __hip_bfloat16 bf16;
using v8s = __attribute__((ext_vector_type(8))) short;   // 8 bf16 (MFMA A/B frag)
using v4f = __attribute__((ext_vector_type(4))) float;   // MFMA C/D frag

// ---------------------------------------------------------------------------
// All four weight transposes in ONE dispatch.
// ---------------------------------------------------------------------------
__global__ __launch_bounds__(256) void transpose_all_kernel(const float* __restrict__ w_attn,
                                                            const float* __restrict__ w_proj,
                                                            const float* __restrict__ w_fc,
                                                            const float* __restrict__ w_out,
                                                            bf16* __restrict__ wext_t,
                                                            bf16* __restrict__ wproj_t,
                                                            bf16* __restrict__ wfc_t,
                                                            bf16* __restrict__ wout_t) {
    int bid = blockIdx.x;
    const float* in; bf16* outp; int K, N, xt, yt;
    if (bid < 1728)      { in = w_attn; outp = wext_t;  K = 768;  N = 2304; xt = bid % 72;          yt = bid / 72; }
    else if (bid < 2304) { int b = bid - 1728; in = w_proj; outp = wproj_t; K = 768;  N = 768;  xt = b % 24; yt = b / 24; }
    else if (bid < 4608) { int b = bid - 2304; in = w_fc;   outp = wfc_t;   K = 768;  N = 3072; xt = b % 96; yt = b / 96; }
    else                 { int b = bid - 4608; in = w_out;  outp = wout_t;  K = 3072; N = 768;  xt = b % 24; yt = b / 24; }
    __shared__ float t[32][33];
    int tx = threadIdx.x & 31, ty = threadIdx.x >> 5;    // 32 x 8
    int n0 = xt * 32, k0 = yt * 32;
    #pragma unroll
    for (int i = ty; i < 32; i += 8)
        t[i][tx] = in[(size_t)(k0 + i) * N + n0 + tx];
    __syncthreads();
    #pragma unroll
    for (int i = ty; i < 32; i += 8)
        outp[(size_t)(n0 + i) * K + k0 + tx] = __float2bfloat16(t[tx][i]);
}

// ---------------------------------------------------------------------------
// Fused FAVOR+ projection weights (cols 2304..3839 of W_ext) + bias_ext.
// ---------------------------------------------------------------------------
__global__ __launch_bounds__(256) void fuse_feat_kernel(const float* __restrict__ w_attn,
                                                        const float* __restrict__ b_attn,
                                                        const float* __restrict__ wfeat,
                                                        bf16* __restrict__ bt_ext,
                                                        float* __restrict__ bias_ext) {
    __shared__ float wfT[64][65];   // wfT[d][m] = scale*wf[m][d]
    __shared__ float Wt[64][65];    // Wt[j][d]
    int t = threadIdx.x;
    int j0 = blockIdx.x * 64, h = blockIdx.y, isK = blockIdx.z;
    int base = isK * DD + h * DHH;
    const float scale = 0.35355339059327373f;  // 64^-0.25
    #pragma unroll
    for (int it = 0; it < 16; it++) {
        int idx = it * 256 + t;
        int m = idx >> 6, d = idx & 63;
        wfT[d][m] = scale * wfeat[m * DHH + d];
        Wt[idx >> 6][idx & 63] = w_attn[(size_t)(j0 + (idx >> 6)) * (3 * DD) + base + (idx & 63)];
    }
    __syncthreads();
    int jl = t & 63, mg = (t >> 6) * 16;
    for (int m = mg; m < mg + 16; m++) {
        float acc = 0.f;
        #pragma unroll 8
        for (int d = 0; d < 64; d++) acc += wfT[d][m] * Wt[jl][d];
        bt_ext[(size_t)(PQOFF + isK * DD + h * DHH + m) * DD + j0 + jl] = __float2bfloat16(acc);
    }
    if (blockIdx.x == 0 && t < 64) {
        float accb = 0.f;
        #pragma unroll 8
        for (int d = 0; d < 64; d++) accb += wfT[d][t] * b_attn[base + d];
        bias_ext[PQOFF + isK * DD + h * DHH + t] = accb;
    }
}

// ---------------------------------------------------------------------------
// LayerNorm: one block per row, 256 threads; f32 in -> bf16 out.
// ---------------------------------------------------------------------------
__global__ __launch_bounds__(256) void ln_kernel(const float* __restrict__ x,
                                                 const float* __restrict__ g,
                                                 const float* __restrict__ bta,
                                                 bf16* __restrict__ out) {
    int row = blockIdx.x;
    int t = threadIdx.x;
    const float* xr = x + (size_t)row * DD;
    float v0 = xr[t], v1 = xr[t + 256], v2 = xr[t + 512];
    float s = v0 + v1 + v2;
    float s2 = v0 * v0 + v1 * v1 + v2 * v2;
    #pragma unroll
    for (int off = 32; off > 0; off >>= 1) {
        s  += __shfl_xor(s,  off, 64);
        s2 += __shfl_xor(s2, off, 64);
    }
    __shared__ float ls[4], ls2[4];
    if ((t & 63) == 0) { ls[t >> 6] = s; ls2[t >> 6] = s2; }
    __syncthreads();
    s  = ls[0] + ls[1] + ls[2] + ls[3];
    s2 = ls2[0] + ls2[1] + ls2[2] + ls2[3];
    float mu  = s * (1.0f / DD);
    float var = s2 * (1.0f / DD) - mu * mu;
    float r = rsqrtf(var + EPS_LN);
    bf16* orow = out + (size_t)row * DD;
    orow[t]       = __float2bfloat16((v0 - mu) * r * g[t]       + bta[t]);
    orow[t + 256] = __float2bfloat16((v1 - mu) * r * g[t + 256] + bta[t + 256]);
    orow[t + 512] = __float2bfloat16((v2 - mu) * r * g[t + 512] + bta[t + 512]);
}

// ---------------------------------------------------------------------------
// MFMA GEMM (r8/r10 proven): C = A @ BT^T + bias (+gelu)(+res).
// 64x64 tile, BK=32, 4 waves; wave w owns rows [16w,16w+16).
// ---------------------------------------------------------------------------
__device__ inline float gelu_tanh(float x) {
    float x3 = x * x * x;
    float u = 0.7978845608028654f * (x + 0.044715f * x3);
    return 0.5f * x * (1.0f + tanhf(u));
}

template <int ACT, int HAS_RES, int OUT_BF16>
__global__ __launch_bounds__(256) void gemm_mfma_kernel(const bf16* __restrict__ A,
                                                        const bf16* __restrict__ BT,
                                                        const float* __restrict__ bias,
                                                        const float* __restrict__ res,
                                                        void* __restrict__ Cout,
                                                        int N, int K) {
    __shared__ bf16 Asl[64][40];
    __shared__ bf16 Bsl[64][40];
    int tid = threadIdx.x;
    int m0 = blockIdx.y * 64, n0 = blockIdx.x * 64;
    int wave = tid >> 6, lane = tid & 63;
    int qm = lane & 15, quad = lane >> 4;
    int sm = tid >> 2, sk = (tid & 3) * 8;

    v4f acc[4] = {{0.f,0.f,0.f,0.f},{0.f,0.f,0.f,0.f},{0.f,0.f,0.f,0.f},{0.f,0.f,0.f,0.f}};

    for (int k0 = 0; k0 < K; k0 += 32) {
        uint4 av = *(const uint4*)(A  + (size_t)(m0 + sm) * K + k0 + sk);
        uint4 bv = *(const uint4*)(BT + (size_t)(n0 + sm) * K + k0 + sk);
        __syncthreads();
        *(uint4*)&Asl[sm][sk] = av;
        *(uint4*)&Bsl[sm][sk] = bv;
        __syncthreads();
        v8s a = *(const v8s*)&Asl[wave * 16 + qm][quad * 8];
        #pragma unroll
        for (int t = 0; t < 4; t++) {
            v8s b = *(const v8s*)&Bsl[t * 16 + qm][quad * 8];
            acc[t] = __builtin_amdgcn_mfma_f32_16x16x32_bf16(a, b, acc[t], 0, 0, 0);
        }
    }

    int col_l = lane & 15;
    #pragma unroll
    for (int t = 0; t < 4; t++) {
        int col = n0 + t * 16 + col_l;
        float bcol = bias[col];
        #pragma unroll
        for (int r = 0; r < 4; r++) {
            int row = m0 + wave * 16 + quad * 4 + r;
            float v = acc[t][r] + bcol;
            if (ACT == 1) v = gelu_tanh(v);
            if (HAS_RES) v += res[(size_t)row * N + col];
            if (OUT_BF16) ((bf16*)Cout)[(size_t)row * N + col] = __float2bfloat16(v);
            else          ((float*)Cout)[(size_t)row * N + col] = v;
        }
    }
}

// ---------------------------------------------------------------------------
// TM=32 x TN=64 GEMM (r10 proven) for proj.
// ---------------------------------------------------------------------------
template <int ACT, int HAS_RES, int OUT_BF16>
__global__ __launch_bounds__(256) void gemm_mfma_m32(const bf16* __restrict__ A,
                                                     const bf16* __restrict__ BT,
                                                     const float* __restrict__ bias,
                                                     const float* __restrict__ res,
                                                     void* __restrict__ Cout,
                                                     int N, int K) {
    __shared__ bf16 Asl[32][40];
    __shared__ bf16 Bsl[64][40];
    int tid = threadIdx.x;
    int m0 = blockIdx.y * 32, n0 = blockIdx.x * 64;
    int wave = tid >> 6, lane = tid & 63;
    int qm = lane & 15, quad = lane >> 4;
    int rowh = (wave & 1) * 16;
    int colh = (wave >> 1) * 32;
    int sm = tid >> 2, sk = (tid & 3) * 8;
    int amr = tid >> 2;

    v4f acc[2] = {{0.f,0.f,0.f,0.f},{0.f,0.f,0.f,0.f}};

    for (int k0 = 0; k0 < K; k0 += 32) {
        uint4 av = {0,0,0,0};
        if (tid < 128) av = *(const uint4*)(A + (size_t)(m0 + amr) * K + k0 + sk);
        uint4 bv = *(const uint4*)(BT + (size_t)(n0 + sm) * K + k0 + sk);
        __syncthreads();
        if (tid < 128) *(uint4*)&Asl[amr][sk] = av;
        *(uint4*)&Bsl[sm][sk] = bv;
        __syncthreads();
        v8s a  = *(const v8s*)&Asl[rowh + qm][quad * 8];
        v8s b0 = *(const v8s*)&Bsl[colh + qm][quad * 8];
        v8s b1 = *(const v8s*)&Bsl[colh + 16 + qm][quad * 8];
        acc[0] = __builtin_amdgcn_mfma_f32_16x16x32_bf16(a, b0, acc[0], 0, 0, 0);
        acc[1] = __builtin_amdgcn_mfma_f32_16x16x32_bf16(a, b1, acc[1], 0, 0, 0);
    }

    #pragma unroll
    for (int ct = 0; ct < 2; ct++) {
        int col = n0 + colh + ct * 16 + qm;
        float bcol = bias[col];
        #pragma unroll
        for (int r = 0; r < 4; r++) {
            int row = m0 + rowh + quad * 4 + r;
            float v = acc[ct][r] + bcol;
            if (ACT == 1) v = gelu_tanh(v);
            if (HAS_RES) v += res[(size_t)row * N + col];
            if (OUT_BF16) ((bf16*)Cout)[(size_t)row * N + col] = __float2bfloat16(v);
            else          ((float*)Cout)[(size_t)row * N + col] = v;
        }
    }
}

// ---------------------------------------------------------------------------
// out init: C = x1 + bias (the split-K GEMM atomically accumulates on top).
// ---------------------------------------------------------------------------
__global__ __launch_bounds__(256) void out_init_kernel(const float* __restrict__ x1,
                                                       const float* __restrict__ bias,
                                                       float* __restrict__ C) {
    int row = blockIdx.x, t = threadIdx.x;
    const float* xr = x1 + (size_t)row * DD;
    float* cr = C + (size_t)row * DD;
    cr[t]       = xr[t]       + bias[t];
    cr[t + 256] = xr[t + 256] + bias[t + 256];
    cr[t + 512] = xr[t + 512] + bias[t + 512];
}

// ---------------------------------------------------------------------------
// Split-K GEMM for out: TM=32, TN=64, K split in SPLITS chunks (blockIdx.z).
// Grid (N/64, BS/32, SPLITS) = 3072 blocks -> ~8-12 blocks/CU: the 24-iter
// latency chains of different blocks overlap (r8-r12 evidence: per-iter cost
// is one miss latency, invariant to block count at <=3 blocks/CU -> raise
// block count AND shorten chains). Epilogue: atomicAdd f32 partials into C.
// ---------------------------------------------------------------------------
template <int SPLITS>
__global__ __launch_bounds__(256) void gemm_splitk_m32(const bf16* __restrict__ A,
                                                       const bf16* __restrict__ BT,
                                                       float* __restrict__ C,
                                                       int N, int K) {
    int kc = K / SPLITS;
    int kbeg = blockIdx.z * kc;
    __shared__ bf16 Asl[32][40];
    __shared__ bf16 Bsl[64][40];
    int tid = threadIdx.x;
    int m0 = blockIdx.y * 32, n0 = blockIdx.x * 64;
    int wave = tid >> 6, lane = tid & 63;
    int qm = lane & 15, quad = lane >> 4;
    int rowh = (wave & 1) * 16;
    int colh = (wave >> 1) * 32;
    int sm = tid >> 2, sk = (tid & 3) * 8;
    int amr = tid >> 2;

    v4f acc[2] = {{0.f,0.f,0.f,0.f},{0.f,0.f,0.f,0.f}};

    for (int k0 = kbeg; k0 < kbeg + kc; k0 += 32) {
        uint4 av = {0,0,0,0};
        if (tid < 128) av = *(const uint4*)(A + (size_t)(m0 + amr) * K + k0 + sk);
        uint4 bv = *(const uint4*)(BT + (size_t)(n0 + sm) * K + k0 + sk);
        __syncthreads();
        if (tid < 128) *(uint4*)&Asl[amr][sk] = av;
        *(uint4*)&Bsl[sm][sk] = bv;
        __syncthreads();
        v8s a  = *(const v8s*)&Asl[rowh + qm][quad * 8];
        v8s b0 = *(const v8s*)&Bsl[colh + qm][quad * 8];
        v8s b1 = *(const v8s*)&Bsl[colh + 16 + qm][quad * 8];
        acc[0] = __builtin_amdgcn_mfma_f32_16x16x32_bf16(a, b0, acc[0], 0, 0, 0);
        acc[1] = __builtin_amdgcn_mfma_f32_16x16x32_bf16(a, b1, acc[1], 0, 0, 0);
    }

    #pragma unroll
    for (int ct = 0; ct < 2; ct++) {
        int col = n0 + colh + ct * 16 + qm;
        #pragma unroll
        for (int r = 0; r < 4; r++) {
            int row = m0 + rowh + quad * 4 + r;
            atomicAdd(&C[(size_t)row * N + col], acc[ct][r]);
        }
    }
}

// ---------------------------------------------------------------------------
// phi in place over proj columns of qkvp.
// ---------------------------------------------------------------------------
__global__ __launch_bounds__(256) void phi_exp_kernel(float* __restrict__ qkvp) {
    int s = blockIdx.x, z = blockIdx.z;
    int b = z >> 1, isK = z & 1;
    int t = threadIdx.x;
    int h = blockIdx.y * 4 + (t >> 6);
    int m = t & 63;
    size_t row = (size_t)b * SS + s;
    float qd = qkvp[row * NQ + isK * DD + h * DHH + m];
    float sq = qd * qd;
    #pragma unroll
    for (int off = 32; off > 0; off >>= 1) sq += __shfl_xor(sq, off, 64);
    sq *= (1.0f / 16.0f);
    size_t pidx = row * NQ + PQOFF + isK * DD + h * DHH + m;
    float proj = qkvp[pidx];
    qkvp[pidx] = __expf(proj - sq) * 0.125f + EPS_PHI;
}

// ---------------------------------------------------------------------------
// Scan phase 1 (MFMA): per (b,h,c): StateT[d][m] = V^T @ phik ; Sk[m] = col-sum.
// ---------------------------------------------------------------------------
__global__ __launch_bounds__(256) void scan_sums_mfma(const float* __restrict__ qkvp,
                                                      float* __restrict__ StateT,
                                                      float* __restrict__ Sk) {
    int c = blockIdx.x, h = blockIdx.y, b = blockIdx.z;
    int bh = b * HH + h;
    int t = threadIdx.x;
    __shared__ bf16 vt[64][72];   // V^T[d][s]
    __shared__ bf16 kt[64][72];   // phik^T[m][s]
    int sr = t >> 4, cq = (t & 15) * 4;
    #pragma unroll
    for (int i = 0; i < 4; i++) {
        int s = sr + 16 * i;
        size_t rowg = ((size_t)b * SS + c * CC + s) * NQ + h * DHH;
        float4 vv = *(const float4*)&qkvp[rowg + VOFF  + cq];
        float4 kv = *(const float4*)&qkvp[rowg + PKOFF + cq];
        vt[cq + 0][s] = __float2bfloat16(vv.x);
        vt[cq + 1][s] = __float2bfloat16(vv.y);
        vt[cq + 2][s] = __float2bfloat16(vv.z);
        vt[cq + 3][s] = __float2bfloat16(vv.w);
        kt[cq + 0][s] = __float2bfloat16(kv.x);
        kt[cq + 1][s] = __float2bfloat16(kv.y);
        kt[cq + 2][s] = __float2bfloat16(kv.z);
        kt[cq + 3][s] = __float2bfloat16(kv.w);
    }
    __syncthreads();
    int wave = t >> 6, lane = t & 63, qm = lane & 15, quad = lane >> 4;
    v4f acc[4] = {{0.f,0.f,0.f,0.f},{0.f,0.f,0.f,0.f},{0.f,0.f,0.f,0.f},{0.f,0.f,0.f,0.f}};
    #pragma unroll
    for (int k0 = 0; k0 < 64; k0 += 32) {
        v8s a = *(const v8s*)&vt[wave * 16 + qm][k0 + quad * 8];
        #pragma unroll
        for (int n = 0; n < 4; n++) {
            v8s bb = *(const v8s*)&kt[n * 16 + qm][k0 + quad * 8];
            acc[n] = __builtin_amdgcn_mfma_f32_16x16x32_bf16(a, bb, acc[n], 0, 0, 0);
        }
    }
    float* dst = StateT + ((size_t)bh * NC + c) * 4096;
    int col_l = lane & 15;
    #pragma unroll
    for (int n = 0; n < 4; n++)
        #pragma unroll
        for (int r = 0; r < 4; r++) {
            int d = wave * 16 + quad * 4 + r;
            dst[d * 64 + n * 16 + col_l] = acc[n][r];
        }
    if (t < 64) {
        float sum = 0.f;
        #pragma unroll 8
        for (int i = 0; i < 64; i++) sum += __bfloat162float(kt[t][i]);
        Sk[((size_t)bh * NC + c) * 64 + t] = sum;
    }
}

// ---------------------------------------------------------------------------
// Scan phase 2: in-place EXCLUSIVE prefix over chunks.
// ---------------------------------------------------------------------------
__global__ __launch_bounds__(256) void scan_prefix_kernel(float* __restrict__ Skv,
                                                          float* __restrict__ Sk) {
    int bh = blockIdx.y;
    int t = blockIdx.x * 256 + threadIdx.x;
    size_t base = (size_t)bh * NC * 4096 + t;
    float acc = 0.f;
    for (int c = 0; c < NC; c++) {
        float v = Skv[base + (size_t)c * 4096];
        Skv[base + (size_t)c * 4096] = acc;
        acc += v;
    }
    if (blockIdx.x == 0 && threadIdx.x < 64) {
        size_t b2 = (size_t)bh * NC * 64 + threadIdx.x;
        float a2 = 0.f;
        for (int c = 0; c < NC; c++) {
            float v = Sk[b2 + (size_t)c * 64];
            Sk[b2 + (size_t)c * 64] = a2;
            a2 += v;
        }
    }
}

// ---------------------------------------------------------------------------
// Scan phase 3 (MFMA): A1 = phiq@phik^T, mask tril -> P;
// acc = phiq@[StateT|SkPre]^T + P@[V|1]; tile4 col0 = den; attn = num/den.
// ---------------------------------------------------------------------------
__global__ __launch_bounds__(256) void scan_chunk_mfma(const float* __restrict__ qkvp,
                                                       const float* __restrict__ StateT,
                                                       const float* __restrict__ SkPre,
                                                       bf16* __restrict__ attn) {
    int c = blockIdx.x, h = blockIdx.y, b = blockIdx.z;
    int bh = b * HH + h;
    int t = threadIdx.x;
    __shared__ bf16 qs[64][72];
    __shared__ bf16 ks[64][72];
    __shared__ bf16 vt[80][72];
    __shared__ bf16 stl[80][72];
    __shared__ bf16 P[64][72];
    int sr = t >> 4, cq = (t & 15) * 4;
    const float* stg = StateT + ((size_t)bh * NC + c) * 4096;
    #pragma unroll
    for (int i = 0; i < 4; i++) {
        int s = sr + 16 * i;
        size_t rowg = ((size_t)b * SS + c * CC + s) * NQ + h * DHH;
        float4 qv = *(const float4*)&qkvp[rowg + PQOFF + cq];
        float4 kv = *(const float4*)&qkvp[rowg + PKOFF + cq];
        float4 vv = *(const float4*)&qkvp[rowg + VOFF  + cq];
        float4 sv = *(const float4*)&stg[s * 64 + cq];
        qs[s][cq + 0] = __float2bfloat16(qv.x);
        qs[s][cq + 1] = __float2bfloat16(qv.y);
        qs[s][cq + 2] = __float2bfloat16(qv.z);
        qs[s][cq + 3] = __float2bfloat16(qv.w);
        ks[s][cq + 0] = __float2bfloat16(kv.x);
        ks[s][cq + 1] = __float2bfloat16(kv.y);
        ks[s][cq + 2] = __float2bfloat16(kv.z);
        ks[s][cq + 3] = __float2bfloat16(kv.w);
        vt[cq + 0][s] = __float2bfloat16(vv.x);
        vt[cq + 1][s] = __float2bfloat16(vv.y);
        vt[cq + 2][s] = __float2bfloat16(vv.z);
        vt[cq + 3][s] = __float2bfloat16(vv.w);
        stl[s][cq + 0] = __float2bfloat16(sv.x);
        stl[s][cq + 1] = __float2bfloat16(sv.y);
        stl[s][cq + 2] = __float2bfloat16(sv.z);
        stl[s][cq + 3] = __float2bfloat16(sv.w);
    }
    {
        int rr = 64 + (t >> 4);
        bf16 one = __float2bfloat16(rr == 64 ? 1.f : 0.f);
        vt[rr][cq + 0] = one; vt[rr][cq + 1] = one;
        vt[rr][cq + 2] = one; vt[rr][cq + 3] = one;
        if (rr == 64) {
            const float* skp = SkPre + ((size_t)bh * NC + c) * 64;
            float4 s4 = *(const float4*)&skp[cq];
            stl[64][cq + 0] = __float2bfloat16(s4.x);
            stl[64][cq + 1] = __float2bfloat16(s4.y);
            stl[64][cq + 2] = __float2bfloat16(s4.z);
            stl[64][cq + 3] = __float2bfloat16(s4.w);
        } else {
            bf16 z = __float2bfloat16(0.f);
            stl[rr][cq + 0] = z; stl[rr][cq + 1] = z;
            stl[rr][cq + 2] = z; stl[rr][cq + 3] = z;
        }
    }
    __syncthreads();
    int wave = t >> 6, lane = t & 63, qm = lane & 15, quad = lane >> 4;
    int col_l = lane & 15;
    int row0 = wave * 16;

    v4f a1[4] = {{0.f,0.f,0.f,0.f},{0.f,0.f,0.f,0.f},{0.f,0.f,0.f,0.f},{0.f,0.f,0.f,0.f}};
    #pragma unroll
    for (int k0 = 0; k0 < 64; k0 += 32) {
        v8s a = *(const v8s*)&qs[row0 + qm][k0 + quad * 8];
        #pragma unroll
        for (int n = 0; n < 4; n++) {
            v8s bb = *(const v8s*)&ks[n * 16 + qm][k0 + quad * 8];
            a1[n] = __builtin_amdgcn_mfma_f32_16x16x32_bf16(a, bb, a1[n], 0, 0, 0);
        }
    }
    #pragma unroll
    for (int n = 0; n < 4; n++)
        #pragma unroll
        for (int r = 0; r < 4; r++) {
            int row = row0 + quad * 4 + r;
            int col = n * 16 + col_l;
            float v = (col <= row) ? a1[n][r] : 0.f;
            P[row][col] = __float2bfloat16(v);
        }
    v4f acc[5] = {{0.f,0.f,0.f,0.f},{0.f,0.f,0.f,0.f},{0.f,0.f,0.f,0.f},
                  {0.f,0.f,0.f,0.f},{0.f,0.f,0.f,0.f}};
    #pragma unroll
    for (int k0 = 0; k0 < 64; k0 += 32) {
        v8s aq = *(const v8s*)&qs[row0 + qm][k0 + quad * 8];
        v8s ap = *(const v8s*)&P [row0 + qm][k0 + quad * 8];
        #pragma unroll
        for (int n = 0; n < 5; n++) {
            v8s b1 = *(const v8s*)&stl[n * 16 + qm][k0 + quad * 8];
            v8s b2 = *(const v8s*)&vt [n * 16 + qm][k0 + quad * 8];
            acc[n] = __builtin_amdgcn_mfma_f32_16x16x32_bf16(aq, b1, acc[n], 0, 0, 0);
            acc[n] = __builtin_amdgcn_mfma_f32_16x16x32_bf16(ap, b2, acc[n], 0, 0, 0);
        }
    }
    float den[4];
    #pragma unroll
    for (int r = 0; r < 4; r++)
        den[r] = __shfl(acc[4][r], (lane >> 4) << 4, 64);
    #pragma unroll
    for (int n = 0; n < 4; n++)
        #pragma unroll
        for (int r = 0; r < 4; r++) {
            int srow = row0 + quad * 4 + r;
            int d = n * 16 + col_l;
            attn[((size_t)b * SS + c * CC + srow) * DD + h * DHH + d] =
                __float2bfloat16(acc[n][r] / den[r]);
        }
}

// ---------------------------------------------------------------------------
extern "C" void kernel_launch(void* const* d_in, const int* in_sizes, int n_in,
                              void* d_out, int out_size, void* d_ws, size_t ws_size,
                              hipStream_t stream) {
    const float* x      = (const float*)d_in[0];
    const float* ln1_g  = (const float*)d_in[1];
    const float* ln1_b  = (const float*)d_in[2];
    const float* w_attn = (const float*)d_in[3];
    const float* b_attn = (const float*)d_in[4];
    const float* w_feat = (const float*)d_in[5];
    const float* w_proj = (const float*)d_in[6];
    const float* b_proj = (const float*)d_in[7];
    const float* ln2_g  = (const float*)d_in[8];
    const float* ln2_b  = (const float*)d_in[9];
    const float* w_fc   = (const float*)d_in[10];
    const float* b_fc   = (const float*)d_in[11];
    const float* w_out  = (const float*)d_in[12];
    const float* b_out  = (const float*)d_in[13];
    float* out = (float*)d_out;

    // f32 region
    float* ws = (float*)d_ws;
    size_t off = 0;
    float* buf_qkvp = ws + off; off += (size_t)BS * NQ;            // 7.86M f32
    float* buf_x1   = ws + off; off += (size_t)BS * DD;            // 1.57M
    float* buf_sk   = ws + off; off += (size_t)BB * HH * NC * MM;  // 24.6K
    float* bias_ext = ws + off; off += NQ;
    // bf16 region
    bf16* wb = (bf16*)(ws + off);
    size_t boff = 0;
    bf16* buf_a_bf    = wb + boff; boff += (size_t)BS * DD;
    bf16* buf_attn_bf = wb + boff; boff += (size_t)BS * DD;
    bf16* wext_t      = wb + boff; boff += (size_t)NQ * DD;
    bf16* wproj_t     = wb + boff; boff += (size_t)DD * DD;
    bf16* wfc_t       = wb + boff; boff += (size_t)DFF * DD;
    bf16* wout_t      = wb + boff; boff += (size_t)DD * DFF;
    // Aliases: StateT (1.57M f32) over buf_x1; fc bf16 over dead qkvp head.
    float* buf_skv   = buf_x1;
    bf16*  buf_fc_bf = (bf16*)buf_qkvp;

    // 0) weight prep (one transpose dispatch + fused FAVOR+ cols + bias copy)
    transpose_all_kernel<<<6912, 256, 0, stream>>>(w_attn, w_proj, w_fc, w_out,
                                                   wext_t, wproj_t, wfc_t, wout_t);
    fuse_feat_kernel<<<dim3(DD / 64, HH, 2), 256, 0, stream>>>(w_attn, b_attn, w_feat, wext_t, bias_ext);
    hipMemcpyAsync(bias_ext, b_attn, 3 * DD * sizeof(float), hipMemcpyDeviceToDevice, stream);

    // 1) a = LN1(x) -> bf16
    ln_kernel<<<BS, 256, 0, stream>>>(x, ln1_g, ln1_b, buf_a_bf);
    // 2) [qkv | proj_q | proj_k] = a @ W_ext + bias_ext  (1920 blocks)
    gemm_mfma_kernel<0, 0, 0><<<dim3(NQ / 64, BS / 64), 256, 0, stream>>>(
        buf_a_bf, wext_t, bias_ext, nullptr, buf_qkvp, NQ, DD);
    // 3) phi in place
    phi_exp_kernel<<<dim3(SS, 3, 2 * BB), 256, 0, stream>>>(buf_qkvp);
    // 4a) per-chunk sums (MFMA)
    scan_sums_mfma<<<dim3(NC, HH, BB), 256, 0, stream>>>(buf_qkvp, buf_skv, buf_sk);
    // 4b) exclusive prefix over chunks
    scan_prefix_kernel<<<dim3(4096 / 256, BB * HH), 256, 0, stream>>>(buf_skv, buf_sk);
    // 4c) per-chunk masked-MFMA scan -> attn (bf16)
    scan_chunk_mfma<<<dim3(NC, HH, BB), 256, 0, stream>>>(
        buf_qkvp, buf_skv, buf_sk, buf_attn_bf);
    // 5) x1 = x + attn @ w_proj + b_proj  (TM=32: 768 blocks)
    gemm_mfma_m32<0, 1, 0><<<dim3(DD / 64, BS / 32), 256, 0, stream>>>(
        buf_attn_bf, wproj_t, b_proj, x, buf_x1, DD, DD);
    // 6) m = LN2(x1) -> bf16
    ln_kernel<<<BS, 256, 0, stream>>>(buf_x1, ln2_g, ln2_b, buf_a_bf);
    // 7) fc = gelu(m @ w_fc + b_fc) -> bf16  (1536 blocks)
    gemm_mfma_kernel<1, 0, 1><<<dim3(DFF / 64, BS / 64), 256, 0, stream>>>(
        buf_a_bf, wfc_t, b_fc, nullptr, buf_fc_bf, DFF, DD);
    // 8) out = x1 + b_out  (init), then split-K=4 atomic GEMM on top
    out_init_kernel<<<BS, 256, 0, stream>>>(buf_x1, b_out, out);
    gemm_splitk_m32<4><<<dim3(DD / 64, BS / 32, 4), 256, 0, stream>>>(
        buf_fc_bf, wout_t, out, DD, DFF);
}

// Round 14
// 272.247 us; speedup vs baseline: 1.9154x; 1.0291x over previous
//
#include <hip/hip_runtime.h>
#include <hip/hip_bf16.h>
#include <math.h>

// Problem constants
#define BB 2
#define SS 1024
#define DD 768
#define HH 12
#define DHH 64
#define MM 64
#define DFF 3072
#define BS (BB*SS)          // 2048 rows
#define EPS_LN 1e-5f
#define EPS_PHI 1e-6f
#define CC 64               // scan chunk length
#define NC (SS/CC)          // 16 chunks
#define NQ 3840             // q,k,v (2304) + proj_q (768) + proj_k (768)
#define PQOFF 2304
#define PKOFF 3072
#define VOFF  1536

typedef __hip_bfloat16 bf16;
using v8s = __attribute__((ext_vector_type(8))) short;   // 8 bf16 (MFMA A/B frag)
using v4f = __attribute__((ext_vector_type(4))) float;   // MFMA C/D frag
struct b4 { bf16 v[4]; };                                // 8B packed bf16 quad

// ---------------------------------------------------------------------------
// All four weight transposes in ONE dispatch.
// ---------------------------------------------------------------------------
__global__ __launch_bounds__(256) void transpose_all_kernel(const float* __restrict__ w_attn,
                                                            const float* __restrict__ w_proj,
                                                            const float* __restrict__ w_fc,
                                                            const float* __restrict__ w_out,
                                                            bf16* __restrict__ wext_t,
                                                            bf16* __restrict__ wproj_t,
                                                            bf16* __restrict__ wfc_t,
                                                            bf16* __restrict__ wout_t) {
    int bid = blockIdx.x;
    const float* in; bf16* outp; int K, N, xt, yt;
    if (bid < 1728)      { in = w_attn; outp = wext_t;  K = 768;  N = 2304; xt = bid % 72;          yt = bid / 72; }
    else if (bid < 2304) { int b = bid - 1728; in = w_proj; outp = wproj_t; K = 768;  N = 768;  xt = b % 24; yt = b / 24; }
    else if (bid < 4608) { int b = bid - 2304; in = w_fc;   outp = wfc_t;   K = 768;  N = 3072; xt = b % 96; yt = b / 96; }
    else                 { int b = bid - 4608; in = w_out;  outp = wout_t;  K = 3072; N = 768;  xt = b % 24; yt = b / 24; }
    __shared__ float t[32][33];
    int tx = threadIdx.x & 31, ty = threadIdx.x >> 5;    // 32 x 8
    int n0 = xt * 32, k0 = yt * 32;
    #pragma unroll
    for (int i = ty; i < 32; i += 8)
        t[i][tx] = in[(size_t)(k0 + i) * N + n0 + tx];
    __syncthreads();
    #pragma unroll
    for (int i = ty; i < 32; i += 8)
        outp[(size_t)(n0 + i) * K + k0 + tx] = __float2bfloat16(t[tx][i]);
}

// ---------------------------------------------------------------------------
// Fused FAVOR+ projection weights (cols 2304..3839 of W_ext) + bias_ext.
// ---------------------------------------------------------------------------
__global__ __launch_bounds__(256) void fuse_feat_kernel(const float* __restrict__ w_attn,
                                                        const float* __restrict__ b_attn,
                                                        const float* __restrict__ wfeat,
                                                        bf16* __restrict__ bt_ext,
                                                        float* __restrict__ bias_ext) {
    __shared__ float wfT[64][65];   // wfT[d][m] = scale*wf[m][d]
    __shared__ float Wt[64][65];    // Wt[j][d]
    int t = threadIdx.x;
    int j0 = blockIdx.x * 64, h = blockIdx.y, isK = blockIdx.z;
    int base = isK * DD + h * DHH;
    const float scale = 0.35355339059327373f;  // 64^-0.25
    #pragma unroll
    for (int it = 0; it < 16; it++) {
        int idx = it * 256 + t;
        int m = idx >> 6, d = idx & 63;
        wfT[d][m] = scale * wfeat[m * DHH + d];
        Wt[idx >> 6][idx & 63] = w_attn[(size_t)(j0 + (idx >> 6)) * (3 * DD) + base + (idx & 63)];
    }
    __syncthreads();
    int jl = t & 63, mg = (t >> 6) * 16;
    for (int m = mg; m < mg + 16; m++) {
        float acc = 0.f;
        #pragma unroll 8
        for (int d = 0; d < 64; d++) acc += wfT[d][m] * Wt[jl][d];
        bt_ext[(size_t)(PQOFF + isK * DD + h * DHH + m) * DD + j0 + jl] = __float2bfloat16(acc);
    }
    if (blockIdx.x == 0 && t < 64) {
        float accb = 0.f;
        #pragma unroll 8
        for (int d = 0; d < 64; d++) accb += wfT[d][t] * b_attn[base + d];
        bias_ext[PQOFF + isK * DD + h * DHH + t] = accb;
    }
}

// ---------------------------------------------------------------------------
// LayerNorm: one block per row, 256 threads; f32 in -> bf16 out.
// ---------------------------------------------------------------------------
__global__ __launch_bounds__(256) void ln_kernel(const float* __restrict__ x,
                                                 const float* __restrict__ g,
                                                 const float* __restrict__ bta,
                                                 bf16* __restrict__ out) {
    int row = blockIdx.x;
    int t = threadIdx.x;
    const float* xr = x + (size_t)row * DD;
    float v0 = xr[t], v1 = xr[t + 256], v2 = xr[t + 512];
    float s = v0 + v1 + v2;
    float s2 = v0 * v0 + v1 * v1 + v2 * v2;
    #pragma unroll
    for (int off = 32; off > 0; off >>= 1) {
        s  += __shfl_xor(s,  off, 64);
        s2 += __shfl_xor(s2, off, 64);
    }
    __shared__ float ls[4], ls2[4];
    if ((t & 63) == 0) { ls[t >> 6] = s; ls2[t >> 6] = s2; }
    __syncthreads();
    s  = ls[0] + ls[1] + ls[2] + ls[3];
    s2 = ls2[0] + ls2[1] + ls2[2] + ls2[3];
    float mu  = s * (1.0f / DD);
    float var = s2 * (1.0f / DD) - mu * mu;
    float r = rsqrtf(var + EPS_LN);
    bf16* orow = out + (size_t)row * DD;
    orow[t]       = __float2bfloat16((v0 - mu) * r * g[t]       + bta[t]);
    orow[t + 256] = __float2bfloat16((v1 - mu) * r * g[t + 256] + bta[t + 256]);
    orow[t + 512] = __float2bfloat16((v2 - mu) * r * g[t + 512] + bta[t + 512]);
}

// ---------------------------------------------------------------------------
// 4x4 supertile swizzle: 16 consecutive block IDs form a 4(n) x 4(m) tile
// group sharing 4 A-bands and 4 B-slices -> duplicated-operand L2 fill /4.
// nx4 = (N-tiles)/4. Returns bx (n-tile), by (m-tile).
// ---------------------------------------------------------------------------
__device__ inline void swizzle44(int bid, int nx4, int& bx, int& by) {
    int g = bid >> 4, r = bid & 15;
    bx = (g % nx4) * 4 + (r & 3);
    by = (g / nx4) * 4 + (r >> 2);
}

// ---------------------------------------------------------------------------
// MFMA GEMM (r8/r10 proven body + swizzle): C = A @ BT^T + bias (+gelu)(+res)
// 64x64 tile, BK=32, 4 waves; wave w owns rows [16w,16w+16).
// ---------------------------------------------------------------------------
__device__ inline float gelu_tanh(float x) {
    float x3 = x * x * x;
    float u = 0.7978845608028654f * (x + 0.044715f * x3);
    return 0.5f * x * (1.0f + tanhf(u));
}

template <int ACT, int HAS_RES, int OUT_BF16>
__global__ __launch_bounds__(256) void gemm_mfma_kernel(const bf16* __restrict__ A,
                                                        const bf16* __restrict__ BT,
                                                        const float* __restrict__ bias,
                                                        const float* __restrict__ res,
                                                        void* __restrict__ Cout,
                                                        int N, int K, int nx4) {
    __shared__ bf16 Asl[64][40];
    __shared__ bf16 Bsl[64][40];
    int bx, by;
    swizzle44(blockIdx.x, nx4, bx, by);
    int tid = threadIdx.x;
    int m0 = by * 64, n0 = bx * 64;
    int wave = tid >> 6, lane = tid & 63;
    int qm = lane & 15, quad = lane >> 4;
    int sm = tid >> 2, sk = (tid & 3) * 8;

    v4f acc[4] = {{0.f,0.f,0.f,0.f},{0.f,0.f,0.f,0.f},{0.f,0.f,0.f,0.f},{0.f,0.f,0.f,0.f}};

    for (int k0 = 0; k0 < K; k0 += 32) {
        uint4 av = *(const uint4*)(A  + (size_t)(m0 + sm) * K + k0 + sk);
        uint4 bv = *(const uint4*)(BT + (size_t)(n0 + sm) * K + k0 + sk);
        __syncthreads();
        *(uint4*)&Asl[sm][sk] = av;
        *(uint4*)&Bsl[sm][sk] = bv;
        __syncthreads();
        v8s a = *(const v8s*)&Asl[wave * 16 + qm][quad * 8];
        #pragma unroll
        for (int t = 0; t < 4; t++) {
            v8s b = *(const v8s*)&Bsl[t * 16 + qm][quad * 8];
            acc[t] = __builtin_amdgcn_mfma_f32_16x16x32_bf16(a, b, acc[t], 0, 0, 0);
        }
    }

    int col_l = lane & 15;
    #pragma unroll
    for (int t = 0; t < 4; t++) {
        int col = n0 + t * 16 + col_l;
        float bcol = bias[col];
        #pragma unroll
        for (int r = 0; r < 4; r++) {
            int row = m0 + wave * 16 + quad * 4 + r;
            float v = acc[t][r] + bcol;
            if (ACT == 1) v = gelu_tanh(v);
            if (HAS_RES) v += res[(size_t)row * N + col];
            if (OUT_BF16) ((bf16*)Cout)[(size_t)row * N + col] = __float2bfloat16(v);
            else          ((float*)Cout)[(size_t)row * N + col] = v;
        }
    }
}

// ---------------------------------------------------------------------------
// TM=32 x TN=64 GEMM (r10 proven body + swizzle) for proj/out (N=768).
// ---------------------------------------------------------------------------
template <int ACT, int HAS_RES, int OUT_BF16>
__global__ __launch_bounds__(256) void gemm_mfma_m32(const bf16* __restrict__ A,
                                                     const bf16* __restrict__ BT,
                                                     const float* __restrict__ bias,
                                                     const float* __restrict__ res,
                                                     void* __restrict__ Cout,
                                                     int N, int K, int nx4) {
    __shared__ bf16 Asl[32][40];
    __shared__ bf16 Bsl[64][40];
    int bx, by;
    swizzle44(blockIdx.x, nx4, bx, by);
    int tid = threadIdx.x;
    int m0 = by * 32, n0 = bx * 64;
    int wave = tid >> 6, lane = tid & 63;
    int qm = lane & 15, quad = lane >> 4;
    int rowh = (wave & 1) * 16;
    int colh = (wave >> 1) * 32;
    int sm = tid >> 2, sk = (tid & 3) * 8;
    int amr = tid >> 2;

    v4f acc[2] = {{0.f,0.f,0.f,0.f},{0.f,0.f,0.f,0.f}};

    for (int k0 = 0; k0 < K; k0 += 32) {
        uint4 av = {0,0,0,0};
        if (tid < 128) av = *(const uint4*)(A + (size_t)(m0 + amr) * K + k0 + sk);
        uint4 bv = *(const uint4*)(BT + (size_t)(n0 + sm) * K + k0 + sk);
        __syncthreads();
        if (tid < 128) *(uint4*)&Asl[amr][sk] = av;
        *(uint4*)&Bsl[sm][sk] = bv;
        __syncthreads();
        v8s a  = *(const v8s*)&Asl[rowh + qm][quad * 8];
        v8s b0 = *(const v8s*)&Bsl[colh + qm][quad * 8];
        v8s b1 = *(const v8s*)&Bsl[colh + 16 + qm][quad * 8];
        acc[0] = __builtin_amdgcn_mfma_f32_16x16x32_bf16(a, b0, acc[0], 0, 0, 0);
        acc[1] = __builtin_amdgcn_mfma_f32_16x16x32_bf16(a, b1, acc[1], 0, 0, 0);
    }

    #pragma unroll
    for (int ct = 0; ct < 2; ct++) {
        int col = n0 + colh + ct * 16 + qm;
        float bcol = bias[col];
        #pragma unroll
        for (int r = 0; r < 4; r++) {
            int row = m0 + rowh + quad * 4 + r;
            float v = acc[ct][r] + bcol;
            if (ACT == 1) v = gelu_tanh(v);
            if (HAS_RES) v += res[(size_t)row * N + col];
            if (OUT_BF16) ((bf16*)Cout)[(size_t)row * N + col] = __float2bfloat16(v);
            else          ((float*)Cout)[(size_t)row * N + col] = v;
        }
    }
}

// ---------------------------------------------------------------------------
// phi in place over proj columns of qkvp (bf16).
// ---------------------------------------------------------------------------
__global__ __launch_bounds__(256) void phi_exp_kernel(bf16* __restrict__ qkvp) {
    int s = blockIdx.x, z = blockIdx.z;
    int b = z >> 1, isK = z & 1;
    int t = threadIdx.x;
    int h = blockIdx.y * 4 + (t >> 6);
    int m = t & 63;
    size_t row = (size_t)b * SS + s;
    float qd = __bfloat162float(qkvp[row * NQ + isK * DD + h * DHH + m]);
    float sq = qd * qd;
    #pragma unroll
    for (int off = 32; off > 0; off >>= 1) sq += __shfl_xor(sq, off, 64);
    sq *= (1.0f / 16.0f);
    size_t pidx = row * NQ + PQOFF + isK * DD + h * DHH + m;
    float proj = __bfloat162float(qkvp[pidx]);
    qkvp[pidx] = __float2bfloat16(__expf(proj - sq) * 0.125f + EPS_PHI);
}

// ---------------------------------------------------------------------------
// Scan phase 1 (MFMA): per (b,h,c): StateT[d][m] = V^T @ phik ; Sk[m] = col-sum.
// qkvp now bf16: direct 8B quad loads, no cast.
// ---------------------------------------------------------------------------
__global__ __launch_bounds__(256) void scan_sums_mfma(const bf16* __restrict__ qkvp,
                                                      float* __restrict__ StateT,
                                                      float* __restrict__ Sk) {
    int c = blockIdx.x, h = blockIdx.y, b = blockIdx.z;
    int bh = b * HH + h;
    int t = threadIdx.x;
    __shared__ bf16 vt[64][72];   // V^T[d][s]
    __shared__ bf16 kt[64][72];   // phik^T[m][s]
    int sr = t >> 4, cq = (t & 15) * 4;
    #pragma unroll
    for (int i = 0; i < 4; i++) {
        int s = sr + 16 * i;
        size_t rowg = ((size_t)b * SS + c * CC + s) * NQ + h * DHH;
        b4 vv = *(const b4*)&qkvp[rowg + VOFF  + cq];
        b4 kv = *(const b4*)&qkvp[rowg + PKOFF + cq];
        #pragma unroll
        for (int j = 0; j < 4; j++) {
            vt[cq + j][s] = vv.v[j];
            kt[cq + j][s] = kv.v[j];
        }
    }
    __syncthreads();
    int wave = t >> 6, lane = t & 63, qm = lane & 15, quad = lane >> 4;
    v4f acc[4] = {{0.f,0.f,0.f,0.f},{0.f,0.f,0.f,0.f},{0.f,0.f,0.f,0.f},{0.f,0.f,0.f,0.f}};
    #pragma unroll
    for (int k0 = 0; k0 < 64; k0 += 32) {
        v8s a = *(const v8s*)&vt[wave * 16 + qm][k0 + quad * 8];
        #pragma unroll
        for (int n = 0; n < 4; n++) {
            v8s bb = *(const v8s*)&kt[n * 16 + qm][k0 + quad * 8];
            acc[n] = __builtin_amdgcn_mfma_f32_16x16x32_bf16(a, bb, acc[n], 0, 0, 0);
        }
    }
    float* dst = StateT + ((size_t)bh * NC + c) * 4096;
    int col_l = lane & 15;
    #pragma unroll
    for (int n = 0; n < 4; n++)
        #pragma unroll
        for (int r = 0; r < 4; r++) {
            int d = wave * 16 + quad * 4 + r;
            dst[d * 64 + n * 16 + col_l] = acc[n][r];
        }
    if (t < 64) {
        float sum = 0.f;
        #pragma unroll 8
        for (int i = 0; i < 64; i++) sum += __bfloat162float(kt[t][i]);
        Sk[((size_t)bh * NC + c) * 64 + t] = sum;
    }
}

// ---------------------------------------------------------------------------
// Scan phase 2: in-place EXCLUSIVE prefix over chunks.
// ---------------------------------------------------------------------------
__global__ __launch_bounds__(256) void scan_prefix_kernel(float* __restrict__ Skv,
                                                          float* __restrict__ Sk) {
    int bh = blockIdx.y;
    int t = blockIdx.x * 256 + threadIdx.x;
    size_t base = (size_t)bh * NC * 4096 + t;
    float acc = 0.f;
    for (int c = 0; c < NC; c++) {
        float v = Skv[base + (size_t)c * 4096];
        Skv[base + (size_t)c * 4096] = acc;
        acc += v;
    }
    if (blockIdx.x == 0 && threadIdx.x < 64) {
        size_t b2 = (size_t)bh * NC * 64 + threadIdx.x;
        float a2 = 0.f;
        for (int c = 0; c < NC; c++) {
            float v = Sk[b2 + (size_t)c * 64];
            Sk[b2 + (size_t)c * 64] = a2;
            a2 += v;
        }
    }
}

// ---------------------------------------------------------------------------
// Scan phase 3 (MFMA): A1 = phiq@phik^T, mask tril -> P;
// acc = phiq@[StateT|SkPre]^T + P@[V|1]; tile4 col0 = den; attn = num/den.
// ---------------------------------------------------------------------------
__global__ __launch_bounds__(256) void scan_chunk_mfma(const bf16* __restrict__ qkvp,
                                                       const float* __restrict__ StateT,
                                                       const float* __restrict__ SkPre,
                                                       bf16* __restrict__ attn) {
    int c = blockIdx.x, h = blockIdx.y, b = blockIdx.z;
    int bh = b * HH + h;
    int t = threadIdx.x;
    __shared__ bf16 qs[64][72];
    __shared__ bf16 ks[64][72];
    __shared__ bf16 vt[80][72];
    __shared__ bf16 stl[80][72];
    __shared__ bf16 P[64][72];
    int sr = t >> 4, cq = (t & 15) * 4;
    const float* stg = StateT + ((size_t)bh * NC + c) * 4096;
    #pragma unroll
    for (int i = 0; i < 4; i++) {
        int s = sr + 16 * i;
        size_t rowg = ((size_t)b * SS + c * CC + s) * NQ + h * DHH;
        b4 qv = *(const b4*)&qkvp[rowg + PQOFF + cq];
        b4 kv = *(const b4*)&qkvp[rowg + PKOFF + cq];
        b4 vv = *(const b4*)&qkvp[rowg + VOFF  + cq];
        float4 sv = *(const float4*)&stg[s * 64 + cq];
        #pragma unroll
        for (int j = 0; j < 4; j++) {
            qs[s][cq + j] = qv.v[j];
            ks[s][cq + j] = kv.v[j];
            vt[cq + j][s] = vv.v[j];
        }
        stl[s][cq + 0] = __float2bfloat16(sv.x);
        stl[s][cq + 1] = __float2bfloat16(sv.y);
        stl[s][cq + 2] = __float2bfloat16(sv.z);
        stl[s][cq + 3] = __float2bfloat16(sv.w);
    }
    {
        int rr = 64 + (t >> 4);
        bf16 one = __float2bfloat16(rr == 64 ? 1.f : 0.f);
        vt[rr][cq + 0] = one; vt[rr][cq + 1] = one;
        vt[rr][cq + 2] = one; vt[rr][cq + 3] = one;
        if (rr == 64) {
            const float* skp = SkPre + ((size_t)bh * NC + c) * 64;
            float4 s4 = *(const float4*)&skp[cq];
            stl[64][cq + 0] = __float2bfloat16(s4.x);
            stl[64][cq + 1] = __float2bfloat16(s4.y);
            stl[64][cq + 2] = __float2bfloat16(s4.z);
            stl[64][cq + 3] = __float2bfloat16(s4.w);
        } else {
            bf16 z = __float2bfloat16(0.f);
            stl[rr][cq + 0] = z; stl[rr][cq + 1] = z;
            stl[rr][cq + 2] = z; stl[rr][cq + 3] = z;
        }
    }
    __syncthreads();
    int wave = t >> 6, lane = t & 63, qm = lane & 15, quad = lane >> 4;
    int col_l = lane & 15;
    int row0 = wave * 16;

    v4f a1[4] = {{0.f,0.f,0.f,0.f},{0.f,0.f,0.f,0.f},{0.f,0.f,0.f,0.f},{0.f,0.f,0.f,0.f}};
    #pragma unroll
    for (int k0 = 0; k0 < 64; k0 += 32) {
        v8s a = *(const v8s*)&qs[row0 + qm][k0 + quad * 8];
        #pragma unroll
        for (int n = 0; n < 4; n++) {
            v8s bb = *(const v8s*)&ks[n * 16 + qm][k0 + quad * 8];
            a1[n] = __builtin_amdgcn_mfma_f32_16x16x32_bf16(a, bb, a1[n], 0, 0, 0);
        }
    }
    #pragma unroll
    for (int n = 0; n < 4; n++)
        #pragma unroll
        for (int r = 0; r < 4; r++) {
            int row = row0 + quad * 4 + r;
            int col = n * 16 + col_l;
            float v = (col <= row) ? a1[n][r] : 0.f;
            P[row][col] = __float2bfloat16(v);
        }
    v4f acc[5] = {{0.f,0.f,0.f,0.f},{0.f,0.f,0.f,0.f},{0.f,0.f,0.f,0.f},
                  {0.f,0.f,0.f,0.f},{0.f,0.f,0.f,0.f}};
    #pragma unroll
    for (int k0 = 0; k0 < 64; k0 += 32) {
        v8s aq = *(const v8s*)&qs[row0 + qm][k0 + quad * 8];
        v8s ap = *(const v8s*)&P [row0 + qm][k0 + quad * 8];
        #pragma unroll
        for (int n = 0; n < 5; n++) {
            v8s b1 = *(const v8s*)&stl[n * 16 + qm][k0 + quad * 8];
            v8s b2 = *(const v8s*)&vt [n * 16 + qm][k0 + quad * 8];
            acc[n] = __builtin_amdgcn_mfma_f32_16x16x32_bf16(aq, b1, acc[n], 0, 0, 0);
            acc[n] = __builtin_amdgcn_mfma_f32_16x16x32_bf16(ap, b2, acc[n], 0, 0, 0);
        }
    }
    float den[4];
    #pragma unroll
    for (int r = 0; r < 4; r++)
        den[r] = __shfl(acc[4][r], (lane >> 4) << 4, 64);
    #pragma unroll
    for (int n = 0; n < 4; n++)
        #pragma unroll
        for (int r = 0; r < 4; r++) {
            int srow = row0 + quad * 4 + r;
            int d = n * 16 + col_l;
            attn[((size_t)b * SS + c * CC + srow) * DD + h * DHH + d] =
                __float2bfloat16(acc[n][r] / den[r]);
        }
}

// ---------------------------------------------------------------------------
extern "C" void kernel_launch(void* const* d_in, const int* in_sizes, int n_in,
                              void* d_out, int out_size, void* d_ws, size_t ws_size,
                              hipStream_t stream) {
    const float* x      = (const float*)d_in[0];
    const float* ln1_g  = (const float*)d_in[1];
    const float* ln1_b  = (const float*)d_in[2];
    const float* w_attn = (const float*)d_in[3];
    const float* b_attn = (const float*)d_in[4];
    const float* w_feat = (const float*)d_in[5];
    const float* w_proj = (const float*)d_in[6];
    const float* b_proj = (const float*)d_in[7];
    const float* ln2_g  = (const float*)d_in[8];
    const float* ln2_b  = (const float*)d_in[9];
    const float* w_fc   = (const float*)d_in[10];
    const float* b_fc   = (const float*)d_in[11];
    const float* w_out  = (const float*)d_in[12];
    const float* b_out  = (const float*)d_in[13];
    float* out = (float*)d_out;

    // f32 region
    float* ws = (float*)d_ws;
    size_t off = 0;
    float* buf_x1   = ws + off; off += (size_t)BS * DD;            // 1.57M f32
    float* buf_sk   = ws + off; off += (size_t)BB * HH * NC * MM;  // 24.6K
    float* bias_ext = ws + off; off += NQ;
    // bf16 region (16B-aligned: preceding counts are multiples of 4)
    bf16* wb = (bf16*)(ws + off);
    size_t boff = 0;
    bf16* buf_qkvp    = wb + boff; boff += (size_t)BS * NQ;        // 7.86M bf16
    bf16* buf_a_bf    = wb + boff; boff += (size_t)BS * DD;
    bf16* buf_attn_bf = wb + boff; boff += (size_t)BS * DD;
    bf16* wext_t      = wb + boff; boff += (size_t)NQ * DD;
    bf16* wproj_t     = wb + boff; boff += (size_t)DD * DD;
    bf16* wfc_t       = wb + boff; boff += (size_t)DFF * DD;
    bf16* wout_t      = wb + boff; boff += (size_t)DD * DFF;
    // Aliases: StateT (1.57M f32) over buf_x1 (x1 written after scan);
    //          fc bf16 (6.29M) over buf_qkvp head (qkvp dead after 4c).
    float* buf_skv   = buf_x1;
    bf16*  buf_fc_bf = buf_qkvp;

    // 0) weight prep (one transpose dispatch + fused FAVOR+ cols + bias copy)
    transpose_all_kernel<<<6912, 256, 0, stream>>>(w_attn, w_proj, w_fc, w_out,
                                                   wext_t, wproj_t, wfc_t, wout_t);
    fuse_feat_kernel<<<dim3(DD / 64, HH, 2), 256, 0, stream>>>(w_attn, b_attn, w_feat, wext_t, bias_ext);
    hipMemcpyAsync(bias_ext, b_attn, 3 * DD * sizeof(float), hipMemcpyDeviceToDevice, stream);

    // 1) a = LN1(x) -> bf16
    ln_kernel<<<BS, 256, 0, stream>>>(x, ln1_g, ln1_b, buf_a_bf);
    // 2) [qkv | proj_q | proj_k] = a @ W_ext + bias_ext -> bf16 (1920 blocks, nx=60)
    gemm_mfma_kernel<0, 0, 1><<<1920, 256, 0, stream>>>(
        buf_a_bf, wext_t, bias_ext, nullptr, buf_qkvp, NQ, DD, 15);
    // 3) phi in place (bf16)
    phi_exp_kernel<<<dim3(SS, 3, 2 * BB), 256, 0, stream>>>(buf_qkvp);
    // 4a) per-chunk sums (MFMA)
    scan_sums_mfma<<<dim3(NC, HH, BB), 256, 0, stream>>>(buf_qkvp, buf_skv, buf_sk);
    // 4b) exclusive prefix over chunks
    scan_prefix_kernel<<<dim3(4096 / 256, BB * HH), 256, 0, stream>>>(buf_skv, buf_sk);
    // 4c) per-chunk masked-MFMA scan -> attn (bf16)
    scan_chunk_mfma<<<dim3(NC, HH, BB), 256, 0, stream>>>(
        buf_qkvp, buf_skv, buf_sk, buf_attn_bf);
    // 5) x1 = x + attn @ w_proj + b_proj  (TM=32: 768 blocks, nx=12)
    gemm_mfma_m32<0, 1, 0><<<768, 256, 0, stream>>>(
        buf_attn_bf, wproj_t, b_proj, x, buf_x1, DD, DD, 3);
    // 6) m = LN2(x1) -> bf16
    ln_kernel<<<BS, 256, 0, stream>>>(buf_x1, ln2_g, ln2_b, buf_a_bf);
    // 7) fc = gelu(m @ w_fc + b_fc) -> bf16 (1536 blocks, nx=48; aliases qkvp)
    gemm_mfma_kernel<1, 0, 1><<<1536, 256, 0, stream>>>(
        buf_a_bf, wfc_t, b_fc, nullptr, buf_fc_bf, DFF, DD, 12);
    // 8) out = x1 + fc @ w_out + b_out  (TM=32: 768 blocks, nx=12, K=3072)
    gemm_mfma_m32<0, 1, 0><<<768, 256, 0, stream>>>(
        buf_fc_bf, wout_t, b_out, buf_x1, out, DD, DFF, 3);
}

// Round 15
// 258.769 us; speedup vs baseline: 2.0151x; 1.0521x over previous
//
#include <hip/hip_runtime.h>
#include <hip/hip_bf16.h>
#include <math.h>

// Problem constants
#define BB 2
#define SS 1024
#define DD 768
#define HH 12
#define DHH 64
#define MM 64
#define DFF 3072
#define BS (BB*SS)          // 2048 rows
#define EPS_LN 1e-5f
#define EPS_PHI 1e-6f
#define CC 64               // scan chunk length
#define NC (SS/CC)          // 16 chunks
#define NQ 3840             // q,k,v (2304) + proj_q (768) + proj_k (768)
#define PQOFF 2304
#define PKOFF 3072
#define VOFF  1536

typedef __hip_bfloat16 bf16;
using v8s = __attribute__((ext_vector_type(8))) short;   // 8 bf16 (MFMA A/B frag)
using v4f = __attribute__((ext_vector_type(4))) float;   // MFMA C/D frag
struct b4 { bf16 v[4]; };                                // 8B packed bf16 quad

// ---------------------------------------------------------------------------
// All four weight transposes in ONE dispatch.
// ---------------------------------------------------------------------------
__global__ __launch_bounds__(256) void transpose_all_kernel(const float* __restrict__ w_attn,
                                                            const float* __restrict__ w_proj,
                                                            const float* __restrict__ w_fc,
                                                            const float* __restrict__ w_out,
                                                            bf16* __restrict__ wext_t,
                                                            bf16* __restrict__ wproj_t,
                                                            bf16* __restrict__ wfc_t,
                                                            bf16* __restrict__ wout_t) {
    int bid = blockIdx.x;
    const float* in; bf16* outp; int K, N, xt, yt;
    if (bid < 1728)      { in = w_attn; outp = wext_t;  K = 768;  N = 2304; xt = bid % 72;          yt = bid / 72; }
    else if (bid < 2304) { int b = bid - 1728; in = w_proj; outp = wproj_t; K = 768;  N = 768;  xt = b % 24; yt = b / 24; }
    else if (bid < 4608) { int b = bid - 2304; in = w_fc;   outp = wfc_t;   K = 768;  N = 3072; xt = b % 96; yt = b / 96; }
    else                 { int b = bid - 4608; in = w_out;  outp = wout_t;  K = 3072; N = 768;  xt = b % 24; yt = b / 24; }
    __shared__ float t[32][33];
    int tx = threadIdx.x & 31, ty = threadIdx.x >> 5;    // 32 x 8
    int n0 = xt * 32, k0 = yt * 32;
    #pragma unroll
    for (int i = ty; i < 32; i += 8)
        t[i][tx] = in[(size_t)(k0 + i) * N + n0 + tx];
    __syncthreads();
    #pragma unroll
    for (int i = ty; i < 32; i += 8)
        outp[(size_t)(n0 + i) * K + k0 + tx] = __float2bfloat16(t[tx][i]);
}

// ---------------------------------------------------------------------------
// Fused FAVOR+ projection weights (cols 2304..3839 of W_ext) + bias_ext.
// ---------------------------------------------------------------------------
__global__ __launch_bounds__(256) void fuse_feat_kernel(const float* __restrict__ w_attn,
                                                        const float* __restrict__ b_attn,
                                                        const float* __restrict__ wfeat,
                                                        bf16* __restrict__ bt_ext,
                                                        float* __restrict__ bias_ext) {
    __shared__ float wfT[64][65];   // wfT[d][m] = scale*wf[m][d]
    __shared__ float Wt[64][65];    // Wt[j][d]
    int t = threadIdx.x;
    int j0 = blockIdx.x * 64, h = blockIdx.y, isK = blockIdx.z;
    int base = isK * DD + h * DHH;
    const float scale = 0.35355339059327373f;  // 64^-0.25
    #pragma unroll
    for (int it = 0; it < 16; it++) {
        int idx = it * 256 + t;
        int m = idx >> 6, d = idx & 63;
        wfT[d][m] = scale * wfeat[m * DHH + d];
        Wt[idx >> 6][idx & 63] = w_attn[(size_t)(j0 + (idx >> 6)) * (3 * DD) + base + (idx & 63)];
    }
    __syncthreads();
    int jl = t & 63, mg = (t >> 6) * 16;
    for (int m = mg; m < mg + 16; m++) {
        float acc = 0.f;
        #pragma unroll 8
        for (int d = 0; d < 64; d++) acc += wfT[d][m] * Wt[jl][d];
        bt_ext[(size_t)(PQOFF + isK * DD + h * DHH + m) * DD + j0 + jl] = __float2bfloat16(acc);
    }
    if (blockIdx.x == 0 && t < 64) {
        float accb = 0.f;
        #pragma unroll 8
        for (int d = 0; d < 64; d++) accb += wfT[d][t] * b_attn[base + d];
        bias_ext[PQOFF + isK * DD + h * DHH + t] = accb;
    }
}

// ---------------------------------------------------------------------------
// LayerNorm: one block per row, 256 threads; f32 in -> bf16 out.
// ---------------------------------------------------------------------------
__global__ __launch_bounds__(256) void ln_kernel(const float* __restrict__ x,
                                                 const float* __restrict__ g,
                                                 const float* __restrict__ bta,
                                                 bf16* __restrict__ out) {
    int row = blockIdx.x;
    int t = threadIdx.x;
    const float* xr = x + (size_t)row * DD;
    float v0 = xr[t], v1 = xr[t + 256], v2 = xr[t + 512];
    float s = v0 + v1 + v2;
    float s2 = v0 * v0 + v1 * v1 + v2 * v2;
    #pragma unroll
    for (int off = 32; off > 0; off >>= 1) {
        s  += __shfl_xor(s,  off, 64);
        s2 += __shfl_xor(s2, off, 64);
    }
    __shared__ float ls[4], ls2[4];
    if ((t & 63) == 0) { ls[t >> 6] = s; ls2[t >> 6] = s2; }
    __syncthreads();
    s  = ls[0] + ls[1] + ls[2] + ls[3];
    s2 = ls2[0] + ls2[1] + ls2[2] + ls2[3];
    float mu  = s * (1.0f / DD);
    float var = s2 * (1.0f / DD) - mu * mu;
    float r = rsqrtf(var + EPS_LN);
    bf16* orow = out + (size_t)row * DD;
    orow[t]       = __float2bfloat16((v0 - mu) * r * g[t]       + bta[t]);
    orow[t + 256] = __float2bfloat16((v1 - mu) * r * g[t + 256] + bta[t + 256]);
    orow[t + 512] = __float2bfloat16((v2 - mu) * r * g[t + 512] + bta[t + 512]);
}

// ---------------------------------------------------------------------------
// 4x4 supertile swizzle: 16 consecutive block IDs form a 4(n) x 4(m) tile
// group sharing 4 A-bands and 4 B-slices -> duplicated-operand L2 fill /4.
// ---------------------------------------------------------------------------
__device__ inline void swizzle44(int bid, int nx4, int& bx, int& by) {
    int g = bid >> 4, r = bid & 15;
    bx = (g % nx4) * 4 + (r & 3);
    by = (g / nx4) * 4 + (r >> 2);
}

// ---------------------------------------------------------------------------
// MFMA GEMM (r8/r10 proven body + swizzle): C = A @ BT^T + bias (+gelu)(+res)
// 64x64 tile, BK=32, 4 waves; wave w owns rows [16w,16w+16).
// ---------------------------------------------------------------------------
__device__ inline float gelu_tanh(float x) {
    float x3 = x * x * x;
    float u = 0.7978845608028654f * (x + 0.044715f * x3);
    return 0.5f * x * (1.0f + tanhf(u));
}

template <int ACT, int HAS_RES, int OUT_BF16>
__global__ __launch_bounds__(256) void gemm_mfma_kernel(const bf16* __restrict__ A,
                                                        const bf16* __restrict__ BT,
                                                        const float* __restrict__ bias,
                                                        const float* __restrict__ res,
                                                        void* __restrict__ Cout,
                                                        int N, int K, int nx4) {
    __shared__ bf16 Asl[64][40];
    __shared__ bf16 Bsl[64][40];
    int bx, by;
    swizzle44(blockIdx.x, nx4, bx, by);
    int tid = threadIdx.x;
    int m0 = by * 64, n0 = bx * 64;
    int wave = tid >> 6, lane = tid & 63;
    int qm = lane & 15, quad = lane >> 4;
    int sm = tid >> 2, sk = (tid & 3) * 8;

    v4f acc[4] = {{0.f,0.f,0.f,0.f},{0.f,0.f,0.f,0.f},{0.f,0.f,0.f,0.f},{0.f,0.f,0.f,0.f}};

    for (int k0 = 0; k0 < K; k0 += 32) {
        uint4 av = *(const uint4*)(A  + (size_t)(m0 + sm) * K + k0 + sk);
        uint4 bv = *(const uint4*)(BT + (size_t)(n0 + sm) * K + k0 + sk);
        __syncthreads();
        *(uint4*)&Asl[sm][sk] = av;
        *(uint4*)&Bsl[sm][sk] = bv;
        __syncthreads();
        v8s a = *(const v8s*)&Asl[wave * 16 + qm][quad * 8];
        #pragma unroll
        for (int t = 0; t < 4; t++) {
            v8s b = *(const v8s*)&Bsl[t * 16 + qm][quad * 8];
            acc[t] = __builtin_amdgcn_mfma_f32_16x16x32_bf16(a, b, acc[t], 0, 0, 0);
        }
    }

    int col_l = lane & 15;
    #pragma unroll
    for (int t = 0; t < 4; t++) {
        int col = n0 + t * 16 + col_l;
        float bcol = bias[col];
        #pragma unroll
        for (int r = 0; r < 4; r++) {
            int row = m0 + wave * 16 + quad * 4 + r;
            float v = acc[t][r] + bcol;
            if (ACT == 1) v = gelu_tanh(v);
            if (HAS_RES) v += res[(size_t)row * N + col];
            if (OUT_BF16) ((bf16*)Cout)[(size_t)row * N + col] = __float2bfloat16(v);
            else          ((float*)Cout)[(size_t)row * N + col] = v;
        }
    }
}

// ---------------------------------------------------------------------------
// TM=32 x TN=64, BK=128 GEMM for proj/out (N=768): 4x fewer chain steps.
// Same proven skeleton (load-at-top / sync / LDS store / sync / MFMA), just
// fatter steps: per thread 2 A-uint4 + 4 B-uint4 issued together -> one
// latency per 128 K-elems instead of per 32. K=3072: 96->24 steps.
// LDS 25.5 KB -> ~6 blocks/CU. Accumulation order identical (K ascending).
// ---------------------------------------------------------------------------
template <int ACT, int HAS_RES, int OUT_BF16>
__global__ __launch_bounds__(256) void gemm_m32_k128(const bf16* __restrict__ A,
                                                     const bf16* __restrict__ BT,
                                                     const float* __restrict__ bias,
                                                     const float* __restrict__ res,
                                                     void* __restrict__ Cout,
                                                     int N, int K, int nx4) {
    __shared__ bf16 Asl[32][136];
    __shared__ bf16 Bsl[64][136];
    int bx, by;
    swizzle44(blockIdx.x, nx4, bx, by);
    int tid = threadIdx.x;
    int m0 = by * 32, n0 = bx * 64;
    int wave = tid >> 6, lane = tid & 63;
    int qm = lane & 15, quad = lane >> 4;
    int rowh = (wave & 1) * 16;
    int colh = (wave >> 1) * 32;
    int ar = tid >> 3, ac = (tid & 7) * 16;   // A: 32 rows x 8 thr, 32B each
    int br = tid >> 2, bc = (tid & 3) * 32;   // B: 64 rows x 4 thr, 64B each

    v4f acc[2] = {{0.f,0.f,0.f,0.f},{0.f,0.f,0.f,0.f}};

    for (int k0 = 0; k0 < K; k0 += 128) {
        const bf16* ap = A  + (size_t)(m0 + ar) * K + k0 + ac;
        const bf16* bp = BT + (size_t)(n0 + br) * K + k0 + bc;
        uint4 av0 = *(const uint4*)(ap);
        uint4 av1 = *(const uint4*)(ap + 8);
        uint4 bv0 = *(const uint4*)(bp);
        uint4 bv1 = *(const uint4*)(bp + 8);
        uint4 bv2 = *(const uint4*)(bp + 16);
        uint4 bv3 = *(const uint4*)(bp + 24);
        __syncthreads();
        *(uint4*)&Asl[ar][ac]      = av0;
        *(uint4*)&Asl[ar][ac + 8]  = av1;
        *(uint4*)&Bsl[br][bc]      = bv0;
        *(uint4*)&Bsl[br][bc + 8]  = bv1;
        *(uint4*)&Bsl[br][bc + 16] = bv2;
        *(uint4*)&Bsl[br][bc + 24] = bv3;
        __syncthreads();
        #pragma unroll
        for (int kc = 0; kc < 4; kc++) {
            v8s a  = *(const v8s*)&Asl[rowh + qm][kc * 32 + quad * 8];
            v8s b0 = *(const v8s*)&Bsl[colh + qm][kc * 32 + quad * 8];
            v8s b1 = *(const v8s*)&Bsl[colh + 16 + qm][kc * 32 + quad * 8];
            acc[0] = __builtin_amdgcn_mfma_f32_16x16x32_bf16(a, b0, acc[0], 0, 0, 0);
            acc[1] = __builtin_amdgcn_mfma_f32_16x16x32_bf16(a, b1, acc[1], 0, 0, 0);
        }
    }

    #pragma unroll
    for (int ct = 0; ct < 2; ct++) {
        int col = n0 + colh + ct * 16 + qm;
        float bcol = bias[col];
        #pragma unroll
        for (int r = 0; r < 4; r++) {
            int row = m0 + rowh + quad * 4 + r;
            float v = acc[ct][r] + bcol;
            if (ACT == 1) v = gelu_tanh(v);
            if (HAS_RES) v += res[(size_t)row * N + col];
            if (OUT_BF16) ((bf16*)Cout)[(size_t)row * N + col] = __float2bfloat16(v);
            else          ((float*)Cout)[(size_t)row * N + col] = v;
        }
    }
}

// ---------------------------------------------------------------------------
// phi in place over proj columns of qkvp (bf16).
// ---------------------------------------------------------------------------
__global__ __launch_bounds__(256) void phi_exp_kernel(bf16* __restrict__ qkvp) {
    int s = blockIdx.x, z = blockIdx.z;
    int b = z >> 1, isK = z & 1;
    int t = threadIdx.x;
    int h = blockIdx.y * 4 + (t >> 6);
    int m = t & 63;
    size_t row = (size_t)b * SS + s;
    float qd = __bfloat162float(qkvp[row * NQ + isK * DD + h * DHH + m]);
    float sq = qd * qd;
    #pragma unroll
    for (int off = 32; off > 0; off >>= 1) sq += __shfl_xor(sq, off, 64);
    sq *= (1.0f / 16.0f);
    size_t pidx = row * NQ + PQOFF + isK * DD + h * DHH + m;
    float proj = __bfloat162float(qkvp[pidx]);
    qkvp[pidx] = __float2bfloat16(__expf(proj - sq) * 0.125f + EPS_PHI);
}

// ---------------------------------------------------------------------------
// Scan phase 1 (MFMA): per (b,h,c): StateT[d][m] = V^T @ phik ; Sk[m] = col-sum.
// ---------------------------------------------------------------------------
__global__ __launch_bounds__(256) void scan_sums_mfma(const bf16* __restrict__ qkvp,
                                                      float* __restrict__ StateT,
                                                      float* __restrict__ Sk) {
    int c = blockIdx.x, h = blockIdx.y, b = blockIdx.z;
    int bh = b * HH + h;
    int t = threadIdx.x;
    __shared__ bf16 vt[64][72];   // V^T[d][s]
    __shared__ bf16 kt[64][72];   // phik^T[m][s]
    int sr = t >> 4, cq = (t & 15) * 4;
    #pragma unroll
    for (int i = 0; i < 4; i++) {
        int s = sr + 16 * i;
        size_t rowg = ((size_t)b * SS + c * CC + s) * NQ + h * DHH;
        b4 vv = *(const b4*)&qkvp[rowg + VOFF  + cq];
        b4 kv = *(const b4*)&qkvp[rowg + PKOFF + cq];
        #pragma unroll
        for (int j = 0; j < 4; j++) {
            vt[cq + j][s] = vv.v[j];
            kt[cq + j][s] = kv.v[j];
        }
    }
    __syncthreads();
    int wave = t >> 6, lane = t & 63, qm = lane & 15, quad = lane >> 4;
    v4f acc[4] = {{0.f,0.f,0.f,0.f},{0.f,0.f,0.f,0.f},{0.f,0.f,0.f,0.f},{0.f,0.f,0.f,0.f}};
    #pragma unroll
    for (int k0 = 0; k0 < 64; k0 += 32) {
        v8s a = *(const v8s*)&vt[wave * 16 + qm][k0 + quad * 8];
        #pragma unroll
        for (int n = 0; n < 4; n++) {
            v8s bb = *(const v8s*)&kt[n * 16 + qm][k0 + quad * 8];
            acc[n] = __builtin_amdgcn_mfma_f32_16x16x32_bf16(a, bb, acc[n], 0, 0, 0);
        }
    }
    float* dst = StateT + ((size_t)bh * NC + c) * 4096;
    int col_l = lane & 15;
    #pragma unroll
    for (int n = 0; n < 4; n++)
        #pragma unroll
        for (int r = 0; r < 4; r++) {
            int d = wave * 16 + quad * 4 + r;
            dst[d * 64 + n * 16 + col_l] = acc[n][r];
        }
    if (t < 64) {
        float sum = 0.f;
        #pragma unroll 8
        for (int i = 0; i < 64; i++) sum += __bfloat162float(kt[t][i]);
        Sk[((size_t)bh * NC + c) * 64 + t] = sum;
    }
}

// ---------------------------------------------------------------------------
// Scan phase 2: in-place EXCLUSIVE prefix over chunks.
// ---------------------------------------------------------------------------
__global__ __launch_bounds__(256) void scan_prefix_kernel(float* __restrict__ Skv,
                                                          float* __restrict__ Sk) {
    int bh = blockIdx.y;
    int t = blockIdx.x * 256 + threadIdx.x;
    size_t base = (size_t)bh * NC * 4096 + t;
    float acc = 0.f;
    for (int c = 0; c < NC; c++) {
        float v = Skv[base + (size_t)c * 4096];
        Skv[base + (size_t)c * 4096] = acc;
        acc += v;
    }
    if (blockIdx.x == 0 && threadIdx.x < 64) {
        size_t b2 = (size_t)bh * NC * 64 + threadIdx.x;
        float a2 = 0.f;
        for (int c = 0; c < NC; c++) {
            float v = Sk[b2 + (size_t)c * 64];
            Sk[b2 + (size_t)c * 64] = a2;
            a2 += v;
        }
    }
}

// ---------------------------------------------------------------------------
// Scan phase 3 (MFMA): A1 = phiq@phik^T, mask tril -> P;
// acc = phiq@[StateT|SkPre]^T + P@[V|1]; tile4 col0 = den; attn = num/den.
// ---------------------------------------------------------------------------
__global__ __launch_bounds__(256) void scan_chunk_mfma(const bf16* __restrict__ qkvp,
                                                       const float* __restrict__ StateT,
                                                       const float* __restrict__ SkPre,
                                                       bf16* __restrict__ attn) {
    int c = blockIdx.x, h = blockIdx.y, b = blockIdx.z;
    int bh = b * HH + h;
    int t = threadIdx.x;
    __shared__ bf16 qs[64][72];
    __shared__ bf16 ks[64][72];
    __shared__ bf16 vt[80][72];
    __shared__ bf16 stl[80][72];
    __shared__ bf16 P[64][72];
    int sr = t >> 4, cq = (t & 15) * 4;
    const float* stg = StateT + ((size_t)bh * NC + c) * 4096;
    #pragma unroll
    for (int i = 0; i < 4; i++) {
        int s = sr + 16 * i;
        size_t rowg = ((size_t)b * SS + c * CC + s) * NQ + h * DHH;
        b4 qv = *(const b4*)&qkvp[rowg + PQOFF + cq];
        b4 kv = *(const b4*)&qkvp[rowg + PKOFF + cq];
        b4 vv = *(const b4*)&qkvp[rowg + VOFF  + cq];
        float4 sv = *(const float4*)&stg[s * 64 + cq];
        #pragma unroll
        for (int j = 0; j < 4; j++) {
            qs[s][cq + j] = qv.v[j];
            ks[s][cq + j] = kv.v[j];
            vt[cq + j][s] = vv.v[j];
        }
        stl[s][cq + 0] = __float2bfloat16(sv.x);
        stl[s][cq + 1] = __float2bfloat16(sv.y);
        stl[s][cq + 2] = __float2bfloat16(sv.z);
        stl[s][cq + 3] = __float2bfloat16(sv.w);
    }
    {
        int rr = 64 + (t >> 4);
        bf16 one = __float2bfloat16(rr == 64 ? 1.f : 0.f);
        vt[rr][cq + 0] = one; vt[rr][cq + 1] = one;
        vt[rr][cq + 2] = one; vt[rr][cq + 3] = one;
        if (rr == 64) {
            const float* skp = SkPre + ((size_t)bh * NC + c) * 64;
            float4 s4 = *(const float4*)&skp[cq];
            stl[64][cq + 0] = __float2bfloat16(s4.x);
            stl[64][cq + 1] = __float2bfloat16(s4.y);
            stl[64][cq + 2] = __float2bfloat16(s4.z);
            stl[64][cq + 3] = __float2bfloat16(s4.w);
        } else {
            bf16 z = __float2bfloat16(0.f);
            stl[rr][cq + 0] = z; stl[rr][cq + 1] = z;
            stl[rr][cq + 2] = z; stl[rr][cq + 3] = z;
        }
    }
    __syncthreads();
    int wave = t >> 6, lane = t & 63, qm = lane & 15, quad = lane >> 4;
    int col_l = lane & 15;
    int row0 = wave * 16;

    v4f a1[4] = {{0.f,0.f,0.f,0.f},{0.f,0.f,0.f,0.f},{0.f,0.f,0.f,0.f},{0.f,0.f,0.f,0.f}};
    #pragma unroll
    for (int k0 = 0; k0 < 64; k0 += 32) {
        v8s a = *(const v8s*)&qs[row0 + qm][k0 + quad * 8];
        #pragma unroll
        for (int n = 0; n < 4; n++) {
            v8s bb = *(const v8s*)&ks[n * 16 + qm][k0 + quad * 8];
            a1[n] = __builtin_amdgcn_mfma_f32_16x16x32_bf16(a, bb, a1[n], 0, 0, 0);
        }
    }
    #pragma unroll
    for (int n = 0; n < 4; n++)
        #pragma unroll
        for (int r = 0; r < 4; r++) {
            int row = row0 + quad * 4 + r;
            int col = n * 16 + col_l;
            float v = (col <= row) ? a1[n][r] : 0.f;
            P[row][col] = __float2bfloat16(v);
        }
    v4f acc[5] = {{0.f,0.f,0.f,0.f},{0.f,0.f,0.f,0.f},{0.f,0.f,0.f,0.f},
                  {0.f,0.f,0.f,0.f},{0.f,0.f,0.f,0.f}};
    #pragma unroll
    for (int k0 = 0; k0 < 64; k0 += 32) {
        v8s aq = *(const v8s*)&qs[row0 + qm][k0 + quad * 8];
        v8s ap = *(const v8s*)&P [row0 + qm][k0 + quad * 8];
        #pragma unroll
        for (int n = 0; n < 5; n++) {
            v8s b1 = *(const v8s*)&stl[n * 16 + qm][k0 + quad * 8];
            v8s b2 = *(const v8s*)&vt [n * 16 + qm][k0 + quad * 8];
            acc[n] = __builtin_amdgcn_mfma_f32_16x16x32_bf16(aq, b1, acc[n], 0, 0, 0);
            acc[n] = __builtin_amdgcn_mfma_f32_16x16x32_bf16(ap, b2, acc[n], 0, 0, 0);
        }
    }
    float den[4];
    #pragma unroll
    for (int r = 0; r < 4; r++)
        den[r] = __shfl(acc[4][r], (lane >> 4) << 4, 64);
    #pragma unroll
    for (int n = 0; n < 4; n++)
        #pragma unroll
        for (int r = 0; r < 4; r++) {
            int srow = row0 + quad * 4 + r;
            int d = n * 16 + col_l;
            attn[((size_t)b * SS + c * CC + srow) * DD + h * DHH + d] =
                __float2bfloat16(acc[n][r] / den[r]);
        }
}

// ---------------------------------------------------------------------------
extern "C" void kernel_launch(void* const* d_in, const int* in_sizes, int n_in,
                              void* d_out, int out_size, void* d_ws, size_t ws_size,
                              hipStream_t stream) {
    const float* x      = (const float*)d_in[0];
    const float* ln1_g  = (const float*)d_in[1];
    const float* ln1_b  = (const float*)d_in[2];
    const float* w_attn = (const float*)d_in[3];
    const float* b_attn = (const float*)d_in[4];
    const float* w_feat = (const float*)d_in[5];
    const float* w_proj = (const float*)d_in[6];
    const float* b_proj = (const float*)d_in[7];
    const float* ln2_g  = (const float*)d_in[8];
    const float* ln2_b  = (const float*)d_in[9];
    const float* w_fc   = (const float*)d_in[10];
    const float* b_fc   = (const float*)d_in[11];
    const float* w_out  = (const float*)d_in[12];
    const float* b_out  = (const float*)d_in[13];
    float* out = (float*)d_out;

    // f32 region
    float* ws = (float*)d_ws;
    size_t off = 0;
    float* buf_x1   = ws + off; off += (size_t)BS * DD;            // 1.57M f32
    float* buf_sk   = ws + off; off += (size_t)BB * HH * NC * MM;  // 24.6K
    float* bias_ext = ws + off; off += NQ;
    // bf16 region (16B-aligned: preceding counts are multiples of 4)
    bf16* wb = (bf16*)(ws + off);
    size_t boff = 0;
    bf16* buf_qkvp    = wb + boff; boff += (size_t)BS * NQ;        // 7.86M bf16
    bf16* buf_a_bf    = wb + boff; boff += (size_t)BS * DD;
    bf16* buf_attn_bf = wb + boff; boff += (size_t)BS * DD;
    bf16* wext_t      = wb + boff; boff += (size_t)NQ * DD;
    bf16* wproj_t     = wb + boff; boff += (size_t)DD * DD;
    bf16* wfc_t      = wb + boff; boff += (size_t)DFF * DD;
    bf16* wout_t      = wb + boff; boff += (size_t)DD * DFF;
    // Aliases: StateT (1.57M f32) over buf_x1 (x1 written after scan);
    //          fc bf16 (6.29M) over buf_qkvp head (qkvp dead after 4c).
    float* buf_skv   = buf_x1;
    bf16*  buf_fc_bf = buf_qkvp;

    // 0) weight prep (one transpose dispatch + fused FAVOR+ cols + bias copy)
    transpose_all_kernel<<<6912, 256, 0, stream>>>(w_attn, w_proj, w_fc, w_out,
                                                   wext_t, wproj_t, wfc_t, wout_t);
    fuse_feat_kernel<<<dim3(DD / 64, HH, 2), 256, 0, stream>>>(w_attn, b_attn, w_feat, wext_t, bias_ext);
    hipMemcpyAsync(bias_ext, b_attn, 3 * DD * sizeof(float), hipMemcpyDeviceToDevice, stream);

    // 1) a = LN1(x) -> bf16
    ln_kernel<<<BS, 256, 0, stream>>>(x, ln1_g, ln1_b, buf_a_bf);
    // 2) [qkv | proj_q | proj_k] = a @ W_ext + bias_ext -> bf16 (1920 blocks, nx=60)
    gemm_mfma_kernel<0, 0, 1><<<1920, 256, 0, stream>>>(
        buf_a_bf, wext_t, bias_ext, nullptr, buf_qkvp, NQ, DD, 15);
    // 3) phi in place (bf16)
    phi_exp_kernel<<<dim3(SS, 3, 2 * BB), 256, 0, stream>>>(buf_qkvp);
    // 4a) per-chunk sums (MFMA)
    scan_sums_mfma<<<dim3(NC, HH, BB), 256, 0, stream>>>(buf_qkvp, buf_skv, buf_sk);
    // 4b) exclusive prefix over chunks
    scan_prefix_kernel<<<dim3(4096 / 256, BB * HH), 256, 0, stream>>>(buf_skv, buf_sk);
    // 4c) per-chunk masked-MFMA scan -> attn (bf16)
    scan_chunk_mfma<<<dim3(NC, HH, BB), 256, 0, stream>>>(
        buf_qkvp, buf_skv, buf_sk, buf_attn_bf);
    // 5) x1 = x + attn @ w_proj + b_proj  (BK=128: 6 chain steps; 768 blocks)
    gemm_m32_k128<0, 1, 0><<<768, 256, 0, stream>>>(
        buf_attn_bf, wproj_t, b_proj, x, buf_x1, DD, DD, 3);
    // 6) m = LN2(x1) -> bf16
    ln_kernel<<<BS, 256, 0, stream>>>(buf_x1, ln2_g, ln2_b, buf_a_bf);
    // 7) fc = gelu(m @ w_fc + b_fc) -> bf16 (1536 blocks, nx=48; aliases qkvp)
    gemm_mfma_kernel<1, 0, 1><<<1536, 256, 0, stream>>>(
        buf_a_bf, wfc_t, b_fc, nullptr, buf_fc_bf, DFF, DD, 12);
    // 8) out = x1 + fc @ w_out + b_out  (BK=128: 24 chain steps; 768 blocks)
    gemm_m32_k128<0, 1, 0><<<768, 256, 0, stream>>>(
        buf_fc_bf, wout_t, b_out, buf_x1, out, DD, DFF, 3);
}

// Round 16
// 257.047 us; speedup vs baseline: 2.0286x; 1.0067x over previous
//
#include <hip/hip_runtime.h>
#include <hip/hip_bf16.h>
#include <math.h>

// Problem constants
#define BB 2
#define SS 1024
#define DD 768
#define HH 12
#define DHH 64
#define MM 64
#define DFF 3072
#define BS (BB*SS)          // 2048 rows
#define EPS_LN 1e-5f
#define EPS_PHI 1e-6f
#define CC 64               // scan chunk length
#define NC (SS/CC)          // 16 chunks
#define NQ 3840             // q,k,v (2304) + proj_q (768) + proj_k (768)
#define PQOFF 2304
#define PKOFF 3072
#define VOFF  1536

typedef __hip_bfloat16 bf16;
using v8s = __attribute__((ext_vector_type(8))) short;   // 8 bf16 (MFMA A/B frag)
using v4f = __attribute__((ext_vector_type(4))) float;   // MFMA C/D frag
struct b4 { bf16 v[4]; };                                // 8B packed bf16 quad

// ---------------------------------------------------------------------------
// All four weight transposes in ONE dispatch.
// ---------------------------------------------------------------------------
__global__ __launch_bounds__(256) void transpose_all_kernel(const float* __restrict__ w_attn,
                                                            const float* __restrict__ w_proj,
                                                            const float* __restrict__ w_fc,
                                                            const float* __restrict__ w_out,
                                                            bf16* __restrict__ wext_t,
                                                            bf16* __restrict__ wproj_t,
                                                            bf16* __restrict__ wfc_t,
                                                            bf16* __restrict__ wout_t) {
    int bid = blockIdx.x;
    const float* in; bf16* outp; int K, N, xt, yt;
    if (bid < 1728)      { in = w_attn; outp = wext_t;  K = 768;  N = 2304; xt = bid % 72;          yt = bid / 72; }
    else if (bid < 2304) { int b = bid - 1728; in = w_proj; outp = wproj_t; K = 768;  N = 768;  xt = b % 24; yt = b / 24; }
    else if (bid < 4608) { int b = bid - 2304; in = w_fc;   outp = wfc_t;   K = 768;  N = 3072; xt = b % 96; yt = b / 96; }
    else                 { int b = bid - 4608; in = w_out;  outp = wout_t;  K = 3072; N = 768;  xt = b % 24; yt = b / 24; }
    __shared__ float t[32][33];
    int tx = threadIdx.x & 31, ty = threadIdx.x >> 5;    // 32 x 8
    int n0 = xt * 32, k0 = yt * 32;
    #pragma unroll
    for (int i = ty; i < 32; i += 8)
        t[i][tx] = in[(size_t)(k0 + i) * N + n0 + tx];
    __syncthreads();
    #pragma unroll
    for (int i = ty; i < 32; i += 8)
        outp[(size_t)(n0 + i) * K + k0 + tx] = __float2bfloat16(t[tx][i]);
}

// ---------------------------------------------------------------------------
// Fused FAVOR+ projection weights (cols 2304..3839 of W_ext) + bias_ext.
// ---------------------------------------------------------------------------
__global__ __launch_bounds__(256) void fuse_feat_kernel(const float* __restrict__ w_attn,
                                                        const float* __restrict__ b_attn,
                                                        const float* __restrict__ wfeat,
                                                        bf16* __restrict__ bt_ext,
                                                        float* __restrict__ bias_ext) {
    __shared__ float wfT[64][65];   // wfT[d][m] = scale*wf[m][d]
    __shared__ float Wt[64][65];    // Wt[j][d]
    int t = threadIdx.x;
    int j0 = blockIdx.x * 64, h = blockIdx.y, isK = blockIdx.z;
    int base = isK * DD + h * DHH;
    const float scale = 0.35355339059327373f;  // 64^-0.25
    #pragma unroll
    for (int it = 0; it < 16; it++) {
        int idx = it * 256 + t;
        int m = idx >> 6, d = idx & 63;
        wfT[d][m] = scale * wfeat[m * DHH + d];
        Wt[idx >> 6][idx & 63] = w_attn[(size_t)(j0 + (idx >> 6)) * (3 * DD) + base + (idx & 63)];
    }
    __syncthreads();
    int jl = t & 63, mg = (t >> 6) * 16;
    for (int m = mg; m < mg + 16; m++) {
        float acc = 0.f;
        #pragma unroll 8
        for (int d = 0; d < 64; d++) acc += wfT[d][m] * Wt[jl][d];
        bt_ext[(size_t)(PQOFF + isK * DD + h * DHH + m) * DD + j0 + jl] = __float2bfloat16(acc);
    }
    if (blockIdx.x == 0 && t < 64) {
        float accb = 0.f;
        #pragma unroll 8
        for (int d = 0; d < 64; d++) accb += wfT[d][t] * b_attn[base + d];
        bias_ext[PQOFF + isK * DD + h * DHH + t] = accb;
    }
}

// ---------------------------------------------------------------------------
// LayerNorm: one block per row, 256 threads; f32 in -> bf16 out.
// ---------------------------------------------------------------------------
__global__ __launch_bounds__(256) void ln_kernel(const float* __restrict__ x,
                                                 const float* __restrict__ g,
                                                 const float* __restrict__ bta,
                                                 bf16* __restrict__ out) {
    int row = blockIdx.x;
    int t = threadIdx.x;
    const float* xr = x + (size_t)row * DD;
    float v0 = xr[t], v1 = xr[t + 256], v2 = xr[t + 512];
    float s = v0 + v1 + v2;
    float s2 = v0 * v0 + v1 * v1 + v2 * v2;
    #pragma unroll
    for (int off = 32; off > 0; off >>= 1) {
        s  += __shfl_xor(s,  off, 64);
        s2 += __shfl_xor(s2, off, 64);
    }
    __shared__ float ls[4], ls2[4];
    if ((t & 63) == 0) { ls[t >> 6] = s; ls2[t >> 6] = s2; }
    __syncthreads();
    s  = ls[0] + ls[1] + ls[2] + ls[3];
    s2 = ls2[0] + ls2[1] + ls2[2] + ls2[3];
    float mu  = s * (1.0f / DD);
    float var = s2 * (1.0f / DD) - mu * mu;
    float r = rsqrtf(var + EPS_LN);
    bf16* orow = out + (size_t)row * DD;
    orow[t]       = __float2bfloat16((v0 - mu) * r * g[t]       + bta[t]);
    orow[t + 256] = __float2bfloat16((v1 - mu) * r * g[t + 256] + bta[t + 256]);
    orow[t + 512] = __float2bfloat16((v2 - mu) * r * g[t + 512] + bta[t + 512]);
}

// ---------------------------------------------------------------------------
// 4x4 supertile swizzle.
// ---------------------------------------------------------------------------
__device__ inline void swizzle44(int bid, int nx4, int& bx, int& by) {
    int g = bid >> 4, r = bid & 15;
    bx = (g % nx4) * 4 + (r & 3);
    by = (g / nx4) * 4 + (r >> 2);
}

__device__ inline float gelu_tanh(float x) {
    float x3 = x * x * x;
    float u = 0.7978845608028654f * (x + 0.044715f * x3);
    return 0.5f * x * (1.0f + tanhf(u));
}

// ---------------------------------------------------------------------------
// TM=64 x TN=64, BK=128 GEMM (qkv/fc): 6 chain steps at K=768.
// Fat steps (r14/r15-validated): per thread 4 A-uint4 + 4 B-uint4 issued
// together -> one latency per 128 K-elems; 16 MFMAs between barriers.
// LDS 34.8 KB -> 4 blocks/CU. Accumulation order identical (K ascending).
// ---------------------------------------------------------------------------
template <int ACT, int HAS_RES, int OUT_BF16>
__global__ __launch_bounds__(256) void gemm_k128(const bf16* __restrict__ A,
                                                 const bf16* __restrict__ BT,
                                                 const float* __restrict__ bias,
                                                 const float* __restrict__ res,
                                                 void* __restrict__ Cout,
                                                 int N, int K, int nx4) {
    __shared__ bf16 Asl[64][136];
    __shared__ bf16 Bsl[64][136];
    int bx, by;
    swizzle44(blockIdx.x, nx4, bx, by);
    int tid = threadIdx.x;
    int m0 = by * 64, n0 = bx * 64;
    int wave = tid >> 6, lane = tid & 63;
    int qm = lane & 15, quad = lane >> 4;
    int sr = tid >> 2, sc = (tid & 3) * 32;   // 64 rows x 4 thr, 64B each

    v4f acc[4] = {{0.f,0.f,0.f,0.f},{0.f,0.f,0.f,0.f},{0.f,0.f,0.f,0.f},{0.f,0.f,0.f,0.f}};

    for (int k0 = 0; k0 < K; k0 += 128) {
        const bf16* ap = A  + (size_t)(m0 + sr) * K + k0 + sc;
        const bf16* bp = BT + (size_t)(n0 + sr) * K + k0 + sc;
        uint4 av0 = *(const uint4*)(ap);
        uint4 av1 = *(const uint4*)(ap + 8);
        uint4 av2 = *(const uint4*)(ap + 16);
        uint4 av3 = *(const uint4*)(ap + 24);
        uint4 bv0 = *(const uint4*)(bp);
        uint4 bv1 = *(const uint4*)(bp + 8);
        uint4 bv2 = *(const uint4*)(bp + 16);
        uint4 bv3 = *(const uint4*)(bp + 24);
        __syncthreads();
        *(uint4*)&Asl[sr][sc]      = av0;
        *(uint4*)&Asl[sr][sc + 8]  = av1;
        *(uint4*)&Asl[sr][sc + 16] = av2;
        *(uint4*)&Asl[sr][sc + 24] = av3;
        *(uint4*)&Bsl[sr][sc]      = bv0;
        *(uint4*)&Bsl[sr][sc + 8]  = bv1;
        *(uint4*)&Bsl[sr][sc + 16] = bv2;
        *(uint4*)&Bsl[sr][sc + 24] = bv3;
        __syncthreads();
        #pragma unroll
        for (int kc = 0; kc < 4; kc++) {
            v8s a = *(const v8s*)&Asl[wave * 16 + qm][kc * 32 + quad * 8];
            #pragma unroll
            for (int n = 0; n < 4; n++) {
                v8s b = *(const v8s*)&Bsl[n * 16 + qm][kc * 32 + quad * 8];
                acc[n] = __builtin_amdgcn_mfma_f32_16x16x32_bf16(a, b, acc[n], 0, 0, 0);
            }
        }
    }

    int col_l = lane & 15;
    #pragma unroll
    for (int t = 0; t < 4; t++) {
        int col = n0 + t * 16 + col_l;
        float bcol = bias[col];
        #pragma unroll
        for (int r = 0; r < 4; r++) {
            int row = m0 + wave * 16 + quad * 4 + r;
            float v = acc[t][r] + bcol;
            if (ACT == 1) v = gelu_tanh(v);
            if (HAS_RES) v += res[(size_t)row * N + col];
            if (OUT_BF16) ((bf16*)Cout)[(size_t)row * N + col] = __float2bfloat16(v);
            else          ((float*)Cout)[(size_t)row * N + col] = v;
        }
    }
}

// ---------------------------------------------------------------------------
// TM=32 x TN=64, BK=128 GEMM (proj/out, N=768) — r15 proven.
// ---------------------------------------------------------------------------
template <int ACT, int HAS_RES, int OUT_BF16>
__global__ __launch_bounds__(256) void gemm_m32_k128(const bf16* __restrict__ A,
                                                     const bf16* __restrict__ BT,
                                                     const float* __restrict__ bias,
                                                     const float* __restrict__ res,
                                                     void* __restrict__ Cout,
                                                     int N, int K, int nx4) {
    __shared__ bf16 Asl[32][136];
    __shared__ bf16 Bsl[64][136];
    int bx, by;
    swizzle44(blockIdx.x, nx4, bx, by);
    int tid = threadIdx.x;
    int m0 = by * 32, n0 = bx * 64;
    int wave = tid >> 6, lane = tid & 63;
    int qm = lane & 15, quad = lane >> 4;
    int rowh = (wave & 1) * 16;
    int colh = (wave >> 1) * 32;
    int ar = tid >> 3, ac = (tid & 7) * 16;   // A: 32 rows x 8 thr, 32B each
    int br = tid >> 2, bc = (tid & 3) * 32;   // B: 64 rows x 4 thr, 64B each

    v4f acc[2] = {{0.f,0.f,0.f,0.f},{0.f,0.f,0.f,0.f}};

    for (int k0 = 0; k0 < K; k0 += 128) {
        const bf16* ap = A  + (size_t)(m0 + ar) * K + k0 + ac;
        const bf16* bp = BT + (size_t)(n0 + br) * K + k0 + bc;
        uint4 av0 = *(const uint4*)(ap);
        uint4 av1 = *(const uint4*)(ap + 8);
        uint4 bv0 = *(const uint4*)(bp);
        uint4 bv1 = *(const uint4*)(bp + 8);
        uint4 bv2 = *(const uint4*)(bp + 16);
        uint4 bv3 = *(const uint4*)(bp + 24);
        __syncthreads();
        *(uint4*)&Asl[ar][ac]      = av0;
        *(uint4*)&Asl[ar][ac + 8]  = av1;
        *(uint4*)&Bsl[br][bc]      = bv0;
        *(uint4*)&Bsl[br][bc + 8]  = bv1;
        *(uint4*)&Bsl[br][bc + 16] = bv2;
        *(uint4*)&Bsl[br][bc + 24] = bv3;
        __syncthreads();
        #pragma unroll
        for (int kc = 0; kc < 4; kc++) {
            v8s a  = *(const v8s*)&Asl[rowh + qm][kc * 32 + quad * 8];
            v8s b0 = *(const v8s*)&Bsl[colh + qm][kc * 32 + quad * 8];
            v8s b1 = *(const v8s*)&Bsl[colh + 16 + qm][kc * 32 + quad * 8];
            acc[0] = __builtin_amdgcn_mfma_f32_16x16x32_bf16(a, b0, acc[0], 0, 0, 0);
            acc[1] = __builtin_amdgcn_mfma_f32_16x16x32_bf16(a, b1, acc[1], 0, 0, 0);
        }
    }

    #pragma unroll
    for (int ct = 0; ct < 2; ct++) {
        int col = n0 + colh + ct * 16 + qm;
        float bcol = bias[col];
        #pragma unroll
        for (int r = 0; r < 4; r++) {
            int row = m0 + rowh + quad * 4 + r;
            float v = acc[ct][r] + bcol;
            if (ACT == 1) v = gelu_tanh(v);
            if (HAS_RES) v += res[(size_t)row * N + col];
            if (OUT_BF16) ((bf16*)Cout)[(size_t)row * N + col] = __float2bfloat16(v);
            else          ((float*)Cout)[(size_t)row * N + col] = v;
        }
    }
}

// ---------------------------------------------------------------------------
// phi in place over proj columns of qkvp (bf16).
// ---------------------------------------------------------------------------
__global__ __launch_bounds__(256) void phi_exp_kernel(bf16* __restrict__ qkvp) {
    int s = blockIdx.x, z = blockIdx.z;
    int b = z >> 1, isK = z & 1;
    int t = threadIdx.x;
    int h = blockIdx.y * 4 + (t >> 6);
    int m = t & 63;
    size_t row = (size_t)b * SS + s;
    float qd = __bfloat162float(qkvp[row * NQ + isK * DD + h * DHH + m]);
    float sq = qd * qd;
    #pragma unroll
    for (int off = 32; off > 0; off >>= 1) sq += __shfl_xor(sq, off, 64);
    sq *= (1.0f / 16.0f);
    size_t pidx = row * NQ + PQOFF + isK * DD + h * DHH + m;
    float proj = __bfloat162float(qkvp[pidx]);
    qkvp[pidx] = __float2bfloat16(__expf(proj - sq) * 0.125f + EPS_PHI);
}

// ---------------------------------------------------------------------------
// Scan phase 1 (MFMA): per (b,h,c): StateT[d][m] = V^T @ phik ; Sk[m] = col-sum.
// ---------------------------------------------------------------------------
__global__ __launch_bounds__(256) void scan_sums_mfma(const bf16* __restrict__ qkvp,
                                                      float* __restrict__ StateT,
                                                      float* __restrict__ Sk) {
    int c = blockIdx.x, h = blockIdx.y, b = blockIdx.z;
    int bh = b * HH + h;
    int t = threadIdx.x;
    __shared__ bf16 vt[64][72];   // V^T[d][s]
    __shared__ bf16 kt[64][72];   // phik^T[m][s]
    int sr = t >> 4, cq = (t & 15) * 4;
    #pragma unroll
    for (int i = 0; i < 4; i++) {
        int s = sr + 16 * i;
        size_t rowg = ((size_t)b * SS + c * CC + s) * NQ + h * DHH;
        b4 vv = *(const b4*)&qkvp[rowg + VOFF  + cq];
        b4 kv = *(const b4*)&qkvp[rowg + PKOFF + cq];
        #pragma unroll
        for (int j = 0; j < 4; j++) {
            vt[cq + j][s] = vv.v[j];
            kt[cq + j][s] = kv.v[j];
        }
    }
    __syncthreads();
    int wave = t >> 6, lane = t & 63, qm = lane & 15, quad = lane >> 4;
    v4f acc[4] = {{0.f,0.f,0.f,0.f},{0.f,0.f,0.f,0.f},{0.f,0.f,0.f,0.f},{0.f,0.f,0.f,0.f}};
    #pragma unroll
    for (int k0 = 0; k0 < 64; k0 += 32) {
        v8s a = *(const v8s*)&vt[wave * 16 + qm][k0 + quad * 8];
        #pragma unroll
        for (int n = 0; n < 4; n++) {
            v8s bb = *(const v8s*)&kt[n * 16 + qm][k0 + quad * 8];
            acc[n] = __builtin_amdgcn_mfma_f32_16x16x32_bf16(a, bb, acc[n], 0, 0, 0);
        }
    }
    float* dst = StateT + ((size_t)bh * NC + c) * 4096;
    int col_l = lane & 15;
    #pragma unroll
    for (int n = 0; n < 4; n++)
        #pragma unroll
        for (int r = 0; r < 4; r++) {
            int d = wave * 16 + quad * 4 + r;
            dst[d * 64 + n * 16 + col_l] = acc[n][r];
        }
    if (t < 64) {
        float sum = 0.f;
        #pragma unroll 8
        for (int i = 0; i < 64; i++) sum += __bfloat162float(kt[t][i]);
        Sk[((size_t)bh * NC + c) * 64 + t] = sum;
    }
}

// ---------------------------------------------------------------------------
// Scan phase 2: in-place EXCLUSIVE prefix over chunks.
// ---------------------------------------------------------------------------
__global__ __launch_bounds__(256) void scan_prefix_kernel(float* __restrict__ Skv,
                                                          float* __restrict__ Sk) {
    int bh = blockIdx.y;
    int t = blockIdx.x * 256 + threadIdx.x;
    size_t base = (size_t)bh * NC * 4096 + t;
    float acc = 0.f;
    for (int c = 0; c < NC; c++) {
        float v = Skv[base + (size_t)c * 4096];
        Skv[base + (size_t)c * 4096] = acc;
        acc += v;
    }
    if (blockIdx.x == 0 && threadIdx.x < 64) {
        size_t b2 = (size_t)bh * NC * 64 + threadIdx.x;
        float a2 = 0.f;
        for (int c = 0; c < NC; c++) {
            float v = Sk[b2 + (size_t)c * 64];
            Sk[b2 + (size_t)c * 64] = a2;
            a2 += v;
        }
    }
}

// ---------------------------------------------------------------------------
// Scan phase 3 (MFMA): A1 = phiq@phik^T, mask tril -> P;
// acc = phiq@[StateT|SkPre]^T + P@[V|1]; tile4 col0 = den; attn = num/den.
// ---------------------------------------------------------------------------
__global__ __launch_bounds__(256) void scan_chunk_mfma(const bf16* __restrict__ qkvp,
                                                       const float* __restrict__ StateT,
                                                       const float* __restrict__ SkPre,
                                                       bf16* __restrict__ attn) {
    int c = blockIdx.x, h = blockIdx.y, b = blockIdx.z;
    int bh = b * HH + h;
    int t = threadIdx.x;
    __shared__ bf16 qs[64][72];
    __shared__ bf16 ks[64][72];
    __shared__ bf16 vt[80][72];
    __shared__ bf16 stl[80][72];
    __shared__ bf16 P[64][72];
    int sr = t >> 4, cq = (t & 15) * 4;
    const float* stg = StateT + ((size_t)bh * NC + c) * 4096;
    #pragma unroll
    for (int i = 0; i < 4; i++) {
        int s = sr + 16 * i;
        size_t rowg = ((size_t)b * SS + c * CC + s) * NQ + h * DHH;
        b4 qv = *(const b4*)&qkvp[rowg + PQOFF + cq];
        b4 kv = *(const b4*)&qkvp[rowg + PKOFF + cq];
        b4 vv = *(const b4*)&qkvp[rowg + VOFF  + cq];
        float4 sv = *(const float4*)&stg[s * 64 + cq];
        #pragma unroll
        for (int j = 0; j < 4; j++) {
            qs[s][cq + j] = qv.v[j];
            ks[s][cq + j] = kv.v[j];
            vt[cq + j][s] = vv.v[j];
        }
        stl[s][cq + 0] = __float2bfloat16(sv.x);
        stl[s][cq + 1] = __float2bfloat16(sv.y);
        stl[s][cq + 2] = __float2bfloat16(sv.z);
        stl[s][cq + 3] = __float2bfloat16(sv.w);
    }
    {
        int rr = 64 + (t >> 4);
        bf16 one = __float2bfloat16(rr == 64 ? 1.f : 0.f);
        vt[rr][cq + 0] = one; vt[rr][cq + 1] = one;
        vt[rr][cq + 2] = one; vt[rr][cq + 3] = one;
        if (rr == 64) {
            const float* skp = SkPre + ((size_t)bh * NC + c) * 64;
            float4 s4 = *(const float4*)&skp[cq];
            stl[64][cq + 0] = __float2bfloat16(s4.x);
            stl[64][cq + 1] = __float2bfloat16(s4.y);
            stl[64][cq + 2] = __float2bfloat16(s4.z);
            stl[64][cq + 3] = __float2bfloat16(s4.w);
        } else {
            bf16 z = __float2bfloat16(0.f);
            stl[rr][cq + 0] = z; stl[rr][cq + 1] = z;
            stl[rr][cq + 2] = z; stl[rr][cq + 3] = z;
        }
    }
    __syncthreads();
    int wave = t >> 6, lane = t & 63, qm = lane & 15, quad = lane >> 4;
    int col_l = lane & 15;
    int row0 = wave * 16;

    v4f a1[4] = {{0.f,0.f,0.f,0.f},{0.f,0.f,0.f,0.f},{0.f,0.f,0.f,0.f},{0.f,0.f,0.f,0.f}};
    #pragma unroll
    for (int k0 = 0; k0 < 64; k0 += 32) {
        v8s a = *(const v8s*)&qs[row0 + qm][k0 + quad * 8];
        #pragma unroll
        for (int n = 0; n < 4; n++) {
            v8s bb = *(const v8s*)&ks[n * 16 + qm][k0 + quad * 8];
            a1[n] = __builtin_amdgcn_mfma_f32_16x16x32_bf16(a, bb, a1[n], 0, 0, 0);
        }
    }
    #pragma unroll
    for (int n = 0; n < 4; n++)
        #pragma unroll
        for (int r = 0; r < 4; r++) {
            int row = row0 + quad * 4 + r;
            int col = n * 16 + col_l;
            float v = (col <= row) ? a1[n][r] : 0.f;
            P[row][col] = __float2bfloat16(v);
        }
    v4f acc[5] = {{0.f,0.f,0.f,0.f},{0.f,0.f,0.f,0.f},{0.f,0.f,0.f,0.f},
                  {0.f,0.f,0.f,0.f},{0.f,0.f,0.f,0.f}};
    #pragma unroll
    for (int k0 = 0; k0 < 64; k0 += 32) {
        v8s aq = *(const v8s*)&qs[row0 + qm][k0 + quad * 8];
        v8s ap = *(const v8s*)&P [row0 + qm][k0 + quad * 8];
        #pragma unroll
        for (int n = 0; n < 5; n++) {
            v8s b1 = *(const v8s*)&stl[n * 16 + qm][k0 + quad * 8];
            v8s b2 = *(const v8s*)&vt [n * 16 + qm][k0 + quad * 8];
            acc[n] = __builtin_amdgcn_mfma_f32_16x16x32_bf16(aq, b1, acc[n], 0, 0, 0);
            acc[n] = __builtin_amdgcn_mfma_f32_16x16x32_bf16(ap, b2, acc[n], 0, 0, 0);
        }
    }
    float den[4];
    #pragma unroll
    for (int r = 0; r < 4; r++)
        den[r] = __shfl(acc[4][r], (lane >> 4) << 4, 64);
    #pragma unroll
    for (int n = 0; n < 4; n++)
        #pragma unroll
        for (int r = 0; r < 4; r++) {
            int srow = row0 + quad * 4 + r;
            int d = n * 16 + col_l;
            attn[((size_t)b * SS + c * CC + srow) * DD + h * DHH + d] =
                __float2bfloat16(acc[n][r] / den[r]);
        }
}

// ---------------------------------------------------------------------------
extern "C" void kernel_launch(void* const* d_in, const int* in_sizes, int n_in,
                              void* d_out, int out_size, void* d_ws, size_t ws_size,
                              hipStream_t stream) {
    const float* x      = (const float*)d_in[0];
    const float* ln1_g  = (const float*)d_in[1];
    const float* ln1_b  = (const float*)d_in[2];
    const float* w_attn = (const float*)d_in[3];
    const float* b_attn = (const float*)d_in[4];
    const float* w_feat = (const float*)d_in[5];
    const float* w_proj = (const float*)d_in[6];
    const float* b_proj = (const float*)d_in[7];
    const float* ln2_g  = (const float*)d_in[8];
    const float* ln2_b  = (const float*)d_in[9];
    const float* w_fc   = (const float*)d_in[10];
    const float* b_fc   = (const float*)d_in[11];
    const float* w_out  = (const float*)d_in[12];
    const float* b_out  = (const float*)d_in[13];
    float* out = (float*)d_out;

    // f32 region
    float* ws = (float*)d_ws;
    size_t off = 0;
    float* buf_x1   = ws + off; off += (size_t)BS * DD;            // 1.57M f32
    float* buf_sk   = ws + off; off += (size_t)BB * HH * NC * MM;  // 24.6K
    float* bias_ext = ws + off; off += NQ;
    // bf16 region (16B-aligned: preceding counts are multiples of 4)
    bf16* wb = (bf16*)(ws + off);
    size_t boff = 0;
    bf16* buf_qkvp    = wb + boff; boff += (size_t)BS * NQ;        // 7.86M bf16
    bf16* buf_a_bf    = wb + boff; boff += (size_t)BS * DD;
    bf16* buf_attn_bf = wb + boff; boff += (size_t)BS * DD;
    bf16* wext_t      = wb + boff; boff += (size_t)NQ * DD;
    bf16* wproj_t     = wb + boff; boff += (size_t)DD * DD;
    bf16* wfc_t       = wb + boff; boff += (size_t)DFF * DD;
    bf16* wout_t      = wb + boff; boff += (size_t)DD * DFF;
    // Aliases: StateT (1.57M f32) over buf_x1 (x1 written after scan);
    //          fc bf16 (6.29M) over buf_qkvp head (qkvp dead after 4c).
    float* buf_skv   = buf_x1;
    bf16*  buf_fc_bf = buf_qkvp;

    // 0) weight prep (one transpose dispatch + fused FAVOR+ cols + bias copy)
    transpose_all_kernel<<<6912, 256, 0, stream>>>(w_attn, w_proj, w_fc, w_out,
                                                   wext_t, wproj_t, wfc_t, wout_t);
    fuse_feat_kernel<<<dim3(DD / 64, HH, 2), 256, 0, stream>>>(w_attn, b_attn, w_feat, wext_t, bias_ext);
    hipMemcpyAsync(bias_ext, b_attn, 3 * DD * sizeof(float), hipMemcpyDeviceToDevice, stream);

    // 1) a = LN1(x) -> bf16
    ln_kernel<<<BS, 256, 0, stream>>>(x, ln1_g, ln1_b, buf_a_bf);
    // 2) [qkv | proj_q | proj_k] = a @ W_ext + bias_ext -> bf16
    //    (BK=128: 6 chain steps; 1920 blocks, nx=60)
    gemm_k128<0, 0, 1><<<1920, 256, 0, stream>>>(
        buf_a_bf, wext_t, bias_ext, nullptr, buf_qkvp, NQ, DD, 15);
    // 3) phi in place (bf16)
    phi_exp_kernel<<<dim3(SS, 3, 2 * BB), 256, 0, stream>>>(buf_qkvp);
    // 4a) per-chunk sums (MFMA)
    scan_sums_mfma<<<dim3(NC, HH, BB), 256, 0, stream>>>(buf_qkvp, buf_skv, buf_sk);
    // 4b) exclusive prefix over chunks
    scan_prefix_kernel<<<dim3(4096 / 256, BB * HH), 256, 0, stream>>>(buf_skv, buf_sk);
    // 4c) per-chunk masked-MFMA scan -> attn (bf16)
    scan_chunk_mfma<<<dim3(NC, HH, BB), 256, 0, stream>>>(
        buf_qkvp, buf_skv, buf_sk, buf_attn_bf);
    // 5) x1 = x + attn @ w_proj + b_proj  (BK=128: 6 steps; 768 blocks)
    gemm_m32_k128<0, 1, 0><<<768, 256, 0, stream>>>(
        buf_attn_bf, wproj_t, b_proj, x, buf_x1, DD, DD, 3);
    // 6) m = LN2(x1) -> bf16
    ln_kernel<<<BS, 256, 0, stream>>>(buf_x1, ln2_g, ln2_b, buf_a_bf);
    // 7) fc = gelu(m @ w_fc + b_fc) -> bf16  (BK=128: 6 steps; 1536 blocks)
    gemm_k128<1, 0, 1><<<1536, 256, 0, stream>>>(
        buf_a_bf, wfc_t, b_fc, nullptr, buf_fc_bf, DFF, DD, 12);
    // 8) out = x1 + fc @ w_out + b_out  (BK=128: 24 steps; 768 blocks)
    gemm_m32_k128<0, 1, 0><<<768, 256, 0, stream>>>(
        buf_fc_bf, wout_t, b_out, buf_x1, out, DD, DFF, 3);
}